// Round 1
// baseline (243.884 us; speedup 1.0000x reference)
//
#include <hip/hip_runtime.h>

#define B_   64
#define NQ_  1024
#define L_   128
#define E_   8192
#define M_   (B_*NQ_)
#define LDP  136        // padded LDS row stride (shorts)
#define TILE 2176       // 16*LDP u16 per tile

typedef unsigned short u16;
typedef unsigned int   u32;
typedef unsigned long long u64;
typedef __attribute__((ext_vector_type(8))) short short8;
typedef __attribute__((ext_vector_type(4))) float floatx4;

#define WVB() __builtin_amdgcn_wave_barrier()

__device__ __forceinline__ int imax2(int a, int b) { return a > b ? a : b; }

__device__ __forceinline__ u16 f2bf(float f) {
    union { float f; u32 u; } v; v.f = f;
    return (u16)((v.u + 0x7fffu + ((v.u >> 16) & 1u)) >> 16);
}
__device__ __forceinline__ float bf2f(u16 u) {
    union { u32 u; float f; } v; v.u = ((u32)u) << 16;
    return v.f;
}
__device__ __forceinline__ floatx4 mfma16(short8 a, short8 b, floatx4 c) {
    return __builtin_amdgcn_mfma_f32_16x16x32_bf16(a, b, c, 0, 0, 0);
}
__device__ __forceinline__ short8 sfrag(const u16* t, int r0, int kb, int lane) {
    return *(const short8*)(t + (r0 + (lane & 15)) * LDP + kb * 32 + (lane >> 4) * 8);
}
// fragment-major weight fetch: coalesced 16B/lane from global (L2-hot)
__device__ __forceinline__ short8 wfrag(const u16* wf, int nt, int kb, int lane) {
    return *(const short8*)(wf + (((kb << 3) + nt) * 64 + lane) * 8);
}
__device__ __forceinline__ void frag_flush(const u16* t, u16* wf, int nt, int lane) {
#pragma unroll
    for (int kb = 0; kb < 4; ++kb)
        *(short8*)(wf + (((kb << 3) + nt) * 64 + lane) * 8) = sfrag(t, 0, kb, lane);
}
__device__ __forceinline__ short8 frag_cvt(const float* base, int r0, int ld, int kb, int lane) {
    const float* p = base + (size_t)(r0 + (lane & 15)) * ld + kb * 32 + (lane >> 4) * 8;
    short8 s;
#pragma unroll
    for (int j = 0; j < 8; ++j) s[j] = (short)f2bf(p[j]);
    return s;
}
__device__ __forceinline__ void tile_store(u16* t, const floatx4* acc, int lane) {
    int col = lane & 15, qd = lane >> 4;
#pragma unroll
    for (int nt = 0; nt < 8; ++nt)
#pragma unroll
        for (int r = 0; r < 4; ++r)
            t[(qd * 4 + r) * LDP + nt * 16 + col] = f2bf(acc[nt][r]);
}
__device__ __forceinline__ void tile_flush(const u16* t, u16* g, int lane) {
#pragma unroll
    for (int it = 0; it < 4; ++it) {
        int chunk = it * 64 + lane, row = chunk >> 4, c8 = chunk & 15;
        *(uint4*)(g + (size_t)row * 128 + c8 * 8) = *(const uint4*)(t + row * LDP + c8 * 8);
    }
}

struct P {
    const int* ei; const float* attr; const float* z0;
    const float* e_w1; const float* e_b1; const float* e_w2; const float* e_b2;
    const float* n_w1; const float* n_b1; const float* ln_g; const float* ln_b;
    const float* n_w2; const float* n_b2;
    int* ofs; int* tgt_s; float* a_s; float* degf;
    u16* wf;        // 6 fragment-major slots: 0=Wc0 1=Wd 2=We 3=Wf 4=Wc1 5=n2_1
    u16* w_n20;     // n2_0 row-major (fin GEMV)
    float* wl; float* vb2;
    float* rx; float* rci; float* rcj; float* rh; float* mx0;
    u16* c0t; u16* t1g; u16* ci1; u16* cj1;   // t1g is fragment-major (u64/lane per (tile,nt))
    float* out;
};

// ---------------------------------------------------------------------------
// Setup, 20 blocks (unchanged):
// 0 CSR; 1-2 n2_0 cvt; 3 n2_1->frag; 4-13 product GEMMs (direct global B);
// 14 rx; 15-17 rci/rcj/rh; 18 c0; 19 vb2(vectorized)+wl+zero mx0
// ---------------------------------------------------------------------------
__global__ __launch_bounds__(256) void k_setup(P p) {
    __shared__ __align__(16) char smem[17408];
    int tid = threadIdx.x, blk = blockIdx.x;
    int lane = tid & 63, w = tid >> 6, col = lane & 15, qd = lane >> 4;

    if (blk == 0) {                               // CSR build
        __shared__ int cnt[1024];
        __shared__ int wsum[4];
        __shared__ int flag;
#pragma unroll
        for (int i = 0; i < 4; ++i) cnt[tid + i * 256] = 0;
        if (tid == 0) flag = 1;
        __syncthreads();
        if (tid < 100 && p.ei[2 * tid + 1] != 0) atomicAnd(&flag, 0);
        __syncthreads();
        int i64 = flag;
        for (int e = tid; e < E_; e += 256) {
            int s = i64 ? p.ei[2 * e] : p.ei[e];
            atomicAdd(&cnt[s], 1);
        }
        __syncthreads();
        int q0 = tid * 4;
        int c0 = cnt[q0], c1 = cnt[q0 + 1], c2 = cnt[q0 + 2], c3 = cnt[q0 + 3];
        int tsum = c0 + c1 + c2 + c3, incl = tsum;
#pragma unroll
        for (int o = 1; o < 64; o <<= 1) {
            int t = __shfl_up(incl, o, 64);
            if (lane >= o) incl += t;
        }
        if (lane == 63) wsum[w] = incl;
        __syncthreads();
        int wo = 0;
        for (int i = 0; i < w; ++i) wo += wsum[i];
        int base = wo + incl - tsum;
        p.ofs[q0] = base; p.ofs[q0 + 1] = base + c0;
        p.ofs[q0 + 2] = base + c0 + c1; p.ofs[q0 + 3] = base + c0 + c1 + c2;
        p.degf[q0] = (float)c0; p.degf[q0 + 1] = (float)c1;
        p.degf[q0 + 2] = (float)c2; p.degf[q0 + 3] = (float)c3;
        if (tid == 0) p.ofs[NQ_] = E_;
        __syncthreads();
        cnt[q0] = base; cnt[q0 + 1] = base + c0;
        cnt[q0 + 2] = base + c0 + c1; cnt[q0 + 3] = base + c0 + c1 + c2;
        __syncthreads();
        for (int e = tid; e < E_; e += 256) {
            int s = i64 ? p.ei[2 * e]        : p.ei[e];
            int t = i64 ? p.ei[2 * (E_ + e)] : p.ei[E_ + e];
            int pos = atomicAdd(&cnt[s], 1);
            p.tgt_s[pos] = t;
            p.a_s[pos]   = p.attr[e];
        }
    } else if (blk <= 2) {                        // n2_0 row-major cvt, 2 halves
        int base = (blk - 1) * 8192;
        for (int idx = tid; idx < 8192; idx += 256)
            p.w_n20[base + idx] = f2bf(p.n_w2[base + idx]);
    } else if (blk == 3) {                        // n2_1 -> fragment-major slot 5
        const float* src = p.n_w2 + 16384;
        u16* dst = p.wf + 5 * 16384;
        for (int pr = w; pr < 32; pr += 4) {      // pr = kb*8+nt
            int kb = pr >> 3, nt = pr & 7;
            const float* s = src + (nt * 16 + col) * 128 + kb * 32 + qd * 8;
            short8 v;
#pragma unroll
            for (int j = 0; j < 8; ++j) v[j] = (short)f2bf(s[j]);
            *(short8*)(dst + (pr * 64 + lane) * 8) = v;
        }
    } else if (blk <= 13) {                       // product GEMMs, direct B loads
        int g = (blk - 4) >> 1, part = (blk - 4) & 1;
        const float* Pm; const float* Q; int ldp; u16* D;
        switch (g) {
            case 0:  Pm = p.n_w1 + 128;             ldp = 256; Q = p.e_w2;         D = p.wf;             break;
            case 1:  Pm = p.n_w1 + 32768 + 128;     ldp = 256; Q = p.e_w2 + 16384; D = p.wf + 4 * 16384; break;
            case 2:  Pm = p.e_w1 + 128 * 257;       ldp = 257; Q = p.n_w2;         D = p.wf + 1 * 16384; break;
            case 3:  Pm = p.e_w1 + 128 * 257 + 128; ldp = 257; Q = p.n_w2;         D = p.wf + 2 * 16384; break;
            default: Pm = p.n_w1 + 32768;           ldp = 256; Q = p.n_w2;         D = p.wf + 3 * 16384; break;
        }
        int tile = part * 4 + w;                  // 0..7, one 16-row tile per wave
        int r0 = tile * 16;
        floatx4 acc[8] = {};
#pragma unroll
        for (int kb = 0; kb < 4; ++kb) {
            short8 a = frag_cvt(Pm, r0, ldp, kb, lane);
#pragma unroll
            for (int nt = 0; nt < 8; ++nt) {
                short8 bq;                        // B[k][n] = Q[k*128+n], coalesced
#pragma unroll
                for (int j = 0; j < 8; ++j)
                    bq[j] = (short)f2bf(Q[(kb * 32 + qd * 8 + j) * 128 + nt * 16 + col]);
                acc[nt] = mfma16(a, bq, acc[nt]);
            }
        }
        u16* slot = (u16*)smem + w * TILE;
        tile_store(slot, acc, lane); WVB();
        frag_flush(slot, D, tile, lane);
    } else if (blk == 14) {                       // rx = z0@n1a0^T + n_b1_0
        int r0 = w * 16;
        floatx4 acc[8] = {};
#pragma unroll
        for (int kb = 0; kb < 4; ++kb) {
            short8 a = frag_cvt(p.z0, r0, 128, kb, lane);
#pragma unroll
            for (int nt = 0; nt < 8; ++nt)
                acc[nt] = mfma16(a, frag_cvt(p.n_w1, nt * 16, 256, kb, lane), acc[nt]);
        }
#pragma unroll
        for (int nt = 0; nt < 8; ++nt) {
            int cg = nt * 16 + col; float bv = p.n_b1[cg];
#pragma unroll
            for (int r = 0; r < 4; ++r) p.rx[(r0 + qd * 4 + r) * 128 + cg] = acc[nt][r] + bv;
        }
    } else if (blk <= 17) {                       // rci/rcj/rh = (z0+n_b2_0)@W^T (+bias)
        int r0 = w * 16;
        const float* Wp; int ld; const float* bias; float* dst;
        if (blk == 15)      { Wp = p.e_w1 + 128 * 257;       ld = 257; bias = p.e_b1 + 128; dst = p.rci; }
        else if (blk == 16) { Wp = p.e_w1 + 128 * 257 + 128; ld = 257; bias = nullptr;      dst = p.rcj; }
        else                { Wp = p.n_w1 + 32768;           ld = 256; bias = p.n_b1 + 128; dst = p.rh;  }
        floatx4 acc[8] = {};
#pragma unroll
        for (int kb = 0; kb < 4; ++kb) {
            short8 a;
            int rr = (r0 + col) * 128, kk = kb * 32 + qd * 8;
#pragma unroll
            for (int j = 0; j < 8; ++j) a[j] = (short)f2bf(p.z0[rr + kk + j] + p.n_b2[kk + j]);
#pragma unroll
            for (int nt = 0; nt < 8; ++nt)
                acc[nt] = mfma16(a, frag_cvt(Wp, nt * 16, ld, kb, lane), acc[nt]);
        }
#pragma unroll
        for (int nt = 0; nt < 8; ++nt) {
            int cg = nt * 16 + col;
            float bv = bias ? bias[cg] : 0.0f;
#pragma unroll
            for (int r = 0; r < 4; ++r) dst[(r0 + qd * 4 + r) * 128 + cg] = acc[nt][r] + bv;
        }
    } else if (blk == 18) {                       // c0 = z0@(W1a0+W1b0)^T + e_b1_0
        int r0 = w * 16;
        floatx4 a1[8] = {};
#pragma unroll
        for (int kb = 0; kb < 4; ++kb) {
            short8 a = frag_cvt(p.z0, r0, 128, kb, lane);
#pragma unroll
            for (int nt = 0; nt < 8; ++nt) {
                a1[nt] = mfma16(a, frag_cvt(p.e_w1,       nt * 16, 257, kb, lane), a1[nt]);
                a1[nt] = mfma16(a, frag_cvt(p.e_w1 + 128, nt * 16, 257, kb, lane), a1[nt]);
            }
        }
#pragma unroll
        for (int nt = 0; nt < 8; ++nt) {
            float bv = p.e_b1[nt * 16 + col];
#pragma unroll
            for (int r = 0; r < 4; ++r) a1[nt][r] += bv;
        }
        u16* slot = (u16*)smem + w * TILE;
        tile_store(slot, a1, lane); WVB();
        tile_flush(slot, p.c0t + (size_t)r0 * 128, lane);
    } else {                                      // vb2 (vectorized) + wl + zero mx0
        int k = tid >> 7, c = tid & 127;
        const float4* wp = (const float4*)(p.n_w1 + k * 32768 + c * 256 + 128);
        const float4* bp = (const float4*)(p.e_b2 + k * 128);
        float s0 = 0.f, s1 = 0.f, s2 = 0.f, s3 = 0.f;
#pragma unroll
        for (int n4 = 0; n4 < 32; ++n4) {
            float4 a = wp[n4], bv = bp[n4];
            s0 += a.x * bv.x; s1 += a.y * bv.y; s2 += a.z * bv.z; s3 += a.w * bv.w;
        }
        p.vb2[tid] = (s0 + s1) + (s2 + s3);
        p.wl[tid]  = p.e_w1[k * 128 * 257 + c * 257 + 256];
        for (int i = tid; i < 8192; i += 256) p.mx0[i] = 0.0f;
    }
}

// ---------------------------------------------------------------------------
// node0, round-0 edge phase FUSED (no gather: S[b,q]=sum_e relu(c0[b]+a*wl0)):
// S computed per-wave straight into LDS tile -> x0 GEMM -> LN -> mx0 atomics;
// ci1 = x0@Wd + rci; cj1 = x0@We + rcj (row-major for node1 gather);
// t1 = x0@Wf + rh -> FRAGMENT-MAJOR global (8B/lane, coalesced)
// ---------------------------------------------------------------------------
__global__ __launch_bounds__(256, 2) void k_node0(P p) {
    __shared__ __align__(16) char smem[52224];
    u16* xt = (u16*)smem;
    u16* ob = (u16*)(smem + 34816);
    int tid = threadIdx.x, lane = tid & 63, w = tid >> 6;
    int col = lane & 15, qd = lane >> 4;
    int blk = blockIdx.x;
    int rowbase = blk * 128 + w * 32;
    int b = blk >> 3;

    // ---- fused round-0 edge aggregation (branchless, 4-q interleaved) ----
    {
        u32 cv = ((const u32*)p.c0t)[b * 64 + lane];
        float cx = bf2f((u16)(cv & 0xffffu)), cy = bf2f((u16)(cv >> 16));
        float2 wl2 = ((const float2*)p.wl)[lane];
        for (int qq = 0; qq < 32; qq += 4) {
            int st[4], en[4];
            float ax[4] = {}, ay[4] = {};
#pragma unroll
            for (int j = 0; j < 4; ++j) {
                int q = (rowbase + qq + j) & (NQ_ - 1);
                st[j] = p.ofs[q]; en[j] = p.ofs[q + 1];
            }
            int mx = imax2(imax2(en[0] - st[0], en[1] - st[1]),
                           imax2(en[2] - st[2], en[3] - st[3]));
            for (int k2 = 0; k2 < mx; ++k2) {
#pragma unroll
                for (int j = 0; j < 4; ++j) {
                    int idx = st[j] + k2, last = en[j] - 1;
                    int safe = idx < en[j] ? idx : (last >= 0 ? last : 0);
                    float a = p.a_s[safe];
                    float vx = fmaxf(cx + a * wl2.x, 0.f);
                    float vy = fmaxf(cy + a * wl2.y, 0.f);
                    bool v = idx < en[j];
                    ax[j] += v ? vx : 0.f;
                    ay[j] += v ? vy : 0.f;
                }
            }
#pragma unroll
            for (int j = 0; j < 4; ++j) {
                int r = qq + j;
                u32* tp = (u32*)(xt + (size_t)(w * 2 + (r >> 4)) * TILE + (r & 15) * LDP);
                tp[lane] = (u32)f2bf(ax[j]) | ((u32)f2bf(ay[j]) << 16);
            }
        }
    }
    WVB();

    floatx4 xa[2][8] = {};
#pragma unroll
    for (int kb = 0; kb < 4; ++kb) {
        short8 Bv[8];
#pragma unroll
        for (int nt = 0; nt < 8; ++nt) Bv[nt] = wfrag(p.wf, nt, kb, lane);
#pragma unroll
        for (int t = 0; t < 2; ++t) {
            short8 a = sfrag(xt + (w * 2 + t) * TILE, 0, kb, lane);
#pragma unroll
            for (int nt = 0; nt < 8; ++nt) xa[t][nt] = mfma16(a, Bv[nt], xa[t][nt]);
        }
    }
    WVB();
    float s8[8] = {};
#pragma unroll
    for (int t = 0; t < 2; ++t) {
#pragma unroll
        for (int nt = 0; nt < 8; ++nt) {
            int cg = nt * 16 + col;
            float base = p.rx[b * 128 + cg], vb = p.vb2[cg];
#pragma unroll
            for (int r = 0; r < 4; ++r) {
                int row = rowbase + t * 16 + qd * 4 + r;
                xa[t][nt][r] = fmaxf(xa[t][nt][r] + base + p.degf[row & (NQ_ - 1)] * vb, 0.f);
            }
        }
#pragma unroll
        for (int r = 0; r < 4; ++r) {
            float s = 0.f, s2 = 0.f;
#pragma unroll
            for (int nt = 0; nt < 8; ++nt) { float v = xa[t][nt][r]; s += v; s2 += v * v; }
#pragma unroll
            for (int o = 1; o < 16; o <<= 1) { s += __shfl_xor(s, o, 64); s2 += __shfl_xor(s2, o, 64); }
            float mu = s * (1.f / 128.f), var = s2 * (1.f / 128.f) - mu * mu;
            float rs = rsqrtf(var + 1e-5f);
#pragma unroll
            for (int nt = 0; nt < 8; ++nt) {
                int cg = nt * 16 + col;
                float xv = (xa[t][nt][r] - mu) * rs * p.ln_g[cg] + p.ln_b[cg];
                xa[t][nt][r] = xv;
                s8[nt] += xv;
            }
        }
        tile_store(xt + (w * 2 + t) * TILE, xa[t], lane);
    }
#pragma unroll
    for (int nt = 0; nt < 8; ++nt) {
        s8[nt] += __shfl_xor(s8[nt], 16, 64);
        s8[nt] += __shfl_xor(s8[nt], 32, 64);
    }
    if (lane < 16) {
#pragma unroll
        for (int nt = 0; nt < 8; ++nt)
            atomicAdd(p.mx0 + b * 128 + nt * 16 + lane, s8[nt]);
    }
    WVB();
#pragma unroll
    for (int ph = 0; ph < 3; ++ph) {
        const u16* wfp = p.wf + ((ph == 0) ? 1 : (ph == 1) ? 2 : 3) * 16384;
        const float* rt = (ph == 0) ? p.rci : (ph == 1) ? p.rcj : p.rh;
        floatx4 ca[2][8] = {};
#pragma unroll
        for (int kb = 0; kb < 4; ++kb) {
            short8 Bv[8];
#pragma unroll
            for (int nt = 0; nt < 8; ++nt) Bv[nt] = wfrag(wfp, nt, kb, lane);
#pragma unroll
            for (int t = 0; t < 2; ++t) {
                short8 a = sfrag(xt + (w * 2 + t) * TILE, 0, kb, lane);
#pragma unroll
                for (int nt = 0; nt < 8; ++nt) ca[t][nt] = mfma16(a, Bv[nt], ca[t][nt]);
            }
        }
#pragma unroll
        for (int t = 0; t < 2; ++t)
#pragma unroll
            for (int nt = 0; nt < 8; ++nt) {
                float rc = rt[b * 128 + nt * 16 + col];
#pragma unroll
                for (int r = 0; r < 4; ++r) ca[t][nt][r] += rc;
            }
        if (ph == 2) {                            // t1 -> fragment-major, 8B/lane
            u64* t1f = (u64*)p.t1g;
#pragma unroll
            for (int t = 0; t < 2; ++t) {
                int tile = blk * 8 + w * 2 + t;
#pragma unroll
                for (int nt = 0; nt < 8; ++nt) {
                    u32 lo = (u32)f2bf(ca[t][nt][0]) | ((u32)f2bf(ca[t][nt][1]) << 16);
                    u32 hi = (u32)f2bf(ca[t][nt][2]) | ((u32)f2bf(ca[t][nt][3]) << 16);
                    t1f[(size_t)(tile * 8 + nt) * 64 + lane] = (u64)lo | ((u64)hi << 32);
                }
            }
        } else {
            u16* dst = (ph == 0) ? p.ci1 : p.cj1;
#pragma unroll
            for (int t = 0; t < 2; ++t) {
                tile_store(ob + w * TILE, ca[t], lane);
                WVB();
                tile_flush(ob + w * TILE, dst + (size_t)(rowbase + t * 16) * 128, lane);
                WVB();
            }
        }
    }
}

// ---------------------------------------------------------------------------
// node1, round-1 edge phase FUSED (gather cj1[b,t], 4-q interleave + (t,a)
// prefetch, branchless): S -> LDS -> x1 GEMM; t1 read fragment-major;
// LN; out += mean(x1@n2_1); fin GEMV
// ---------------------------------------------------------------------------
__global__ __launch_bounds__(256, 2) void k_node1(P p) {
    __shared__ __align__(16) char smem[52224];
    u16* xt = (u16*)smem;
    u16* ob = (u16*)(smem + 34816);
    int tid = threadIdx.x, lane = tid & 63, w = tid >> 6;
    int col = lane & 15, qd = lane >> 4;
    int blk = blockIdx.x;
    int rowbase = blk * 128 + w * 32;
    int b = blk >> 3;

    // ---- fused round-1 edge aggregation ----
    {
        float2 wl2 = ((const float2*)(p.wl + 128))[lane];
        const u32* cip = (const u32*)p.ci1;
        const u32* cjp = (const u32*)p.cj1 + (size_t)b * NQ_ * 64;
        for (int qq = 0; qq < 32; qq += 4) {
            int st[4], en[4];
            float ax[4] = {}, ay[4] = {}, cx[4], cy[4];
#pragma unroll
            for (int j = 0; j < 4; ++j) {
                int row = rowbase + qq + j;
                u32 cv = cip[(size_t)row * 64 + lane];
                cx[j] = bf2f((u16)(cv & 0xffffu)); cy[j] = bf2f((u16)(cv >> 16));
                int q = row & (NQ_ - 1);
                st[j] = p.ofs[q]; en[j] = p.ofs[q + 1];
            }
            int mx = imax2(imax2(en[0] - st[0], en[1] - st[1]),
                           imax2(en[2] - st[2], en[3] - st[3]));
            int tc[4]; float ac[4];
#pragma unroll
            for (int j = 0; j < 4; ++j) {         // prefetch (t,a) for k2=0
                int last = en[j] - 1;
                int safe = st[j] < en[j] ? st[j] : (last >= 0 ? last : 0);
                tc[j] = p.tgt_s[safe]; ac[j] = p.a_s[safe];
            }
            for (int k2 = 0; k2 < mx; ++k2) {
                u32 jv[4];
#pragma unroll
                for (int j = 0; j < 4; ++j)       // 4 independent 256B gathers
                    jv[j] = cjp[(size_t)tc[j] * 64 + lane];
                int tn[4]; float an[4];
#pragma unroll
                for (int j = 0; j < 4; ++j) {     // prefetch (t,a) for k2+1
                    int idx = st[j] + k2 + 1, last = en[j] - 1;
                    int safe = idx < en[j] ? idx : (last >= 0 ? last : 0);
                    tn[j] = p.tgt_s[safe]; an[j] = p.a_s[safe];
                }
#pragma unroll
                for (int j = 0; j < 4; ++j) {
                    float vx = fmaxf(cx[j] + bf2f((u16)(jv[j] & 0xffffu)) + ac[j] * wl2.x, 0.f);
                    float vy = fmaxf(cy[j] + bf2f((u16)(jv[j] >> 16))    + ac[j] * wl2.y, 0.f);
                    bool v = st[j] + k2 < en[j];
                    ax[j] += v ? vx : 0.f;
                    ay[j] += v ? vy : 0.f;
                    tc[j] = tn[j]; ac[j] = an[j];
                }
            }
#pragma unroll
            for (int j = 0; j < 4; ++j) {
                int r = qq + j;
                u32* tp = (u32*)(xt + (size_t)(w * 2 + (r >> 4)) * TILE + (r & 15) * LDP);
                tp[lane] = (u32)f2bf(ax[j]) | ((u32)f2bf(ay[j]) << 16);
            }
        }
    }
    WVB();

    const u16* wc1 = p.wf + 4 * 16384;
    floatx4 xa[2][8] = {};
#pragma unroll
    for (int kb = 0; kb < 4; ++kb) {
        short8 Bv[8];
#pragma unroll
        for (int nt = 0; nt < 8; ++nt) Bv[nt] = wfrag(wc1, nt, kb, lane);
#pragma unroll
        for (int t = 0; t < 2; ++t) {
            short8 a = sfrag(xt + (w * 2 + t) * TILE, 0, kb, lane);
#pragma unroll
            for (int nt = 0; nt < 8; ++nt) xa[t][nt] = mfma16(a, Bv[nt], xa[t][nt]);
        }
    }
    const float* vb21 = p.vb2 + 128;
    const u64* t1f = (const u64*)p.t1g;
#pragma unroll
    for (int t = 0; t < 2; ++t) {
        int tile = blk * 8 + w * 2 + t;
#pragma unroll
        for (int nt = 0; nt < 8; ++nt) {
            int cg = nt * 16 + col;
            float vb = vb21[cg];
            u64 tv = t1f[(size_t)(tile * 8 + nt) * 64 + lane];   // coalesced 8B/lane
            float tvf[4] = { bf2f((u16)tv),         bf2f((u16)(tv >> 16)),
                             bf2f((u16)(tv >> 32)), bf2f((u16)(tv >> 48)) };
#pragma unroll
            for (int r = 0; r < 4; ++r) {
                int row = rowbase + t * 16 + qd * 4 + r;
                xa[t][nt][r] = fmaxf(xa[t][nt][r] + tvf[r] + p.degf[row & (NQ_ - 1)] * vb, 0.f);
            }
        }
#pragma unroll
        for (int r = 0; r < 4; ++r) {
            float s = 0.f, s2 = 0.f;
#pragma unroll
            for (int nt = 0; nt < 8; ++nt) { float v = xa[t][nt][r]; s += v; s2 += v * v; }
#pragma unroll
            for (int o = 1; o < 16; o <<= 1) { s += __shfl_xor(s, o, 64); s2 += __shfl_xor(s2, o, 64); }
            float mu = s * (1.f / 128.f), var = s2 * (1.f / 128.f) - mu * mu;
            float rs = rsqrtf(var + 1e-5f);
#pragma unroll
            for (int nt = 0; nt < 8; ++nt) {
                int cg = nt * 16 + col;
                xa[t][nt][r] = (xa[t][nt][r] - mu) * rs * p.ln_g[128 + cg] + p.ln_b[128 + cg];
            }
        }
    }
    // mean(x1@n2_1): per-wave sequential staging through ob slot
    const u16* n21 = p.wf + 5 * 16384;
    float s8[8] = {};
#pragma unroll
    for (int t = 0; t < 2; ++t) {
        WVB();
        tile_store(ob + w * TILE, xa[t], lane);
        WVB();
        floatx4 ma[8] = {};
#pragma unroll
        for (int kb = 0; kb < 4; ++kb) {
            short8 Bv[8];
#pragma unroll
            for (int nt = 0; nt < 8; ++nt) Bv[nt] = wfrag(n21, nt, kb, lane);
            short8 a = sfrag(ob + w * TILE, 0, kb, lane);
#pragma unroll
            for (int nt = 0; nt < 8; ++nt) ma[nt] = mfma16(a, Bv[nt], ma[nt]);
        }
#pragma unroll
        for (int nt = 0; nt < 8; ++nt)
#pragma unroll
            for (int r = 0; r < 4; ++r) s8[nt] += ma[nt][r];
    }
#pragma unroll
    for (int nt = 0; nt < 8; ++nt) {
        s8[nt] += __shfl_xor(s8[nt], 16, 64);
        s8[nt] += __shfl_xor(s8[nt], 32, 64);
    }
    if (lane < 16) {
#pragma unroll
        for (int nt = 0; nt < 8; ++nt)
            atomicAdd(p.out + b * 128 + nt * 16 + lane, s8[nt] * (1.f / 1024.f));
    }
    // fin: out[b] += z0[b] + n_b2_0 + n_b2_1 + mx0[b]@n2_0^T / 1024  (vectorized)
    if ((blk & 7) == 0 && tid < 128) {
        int c = tid;
        const float* mx = p.mx0 + b * 128;
        float s = 0.f;
#pragma unroll
        for (int k8 = 0; k8 < 16; ++k8) {
            short8 wv = *(const short8*)(p.w_n20 + c * 128 + k8 * 8);
            const float* mxp = mx + k8 * 8;
#pragma unroll
            for (int j = 0; j < 8; ++j) s += mxp[j] * bf2f((u16)wv[j]);
        }
        float acc = p.z0[b * 128 + c] + p.n_b2[c] + p.n_b2[128 + c] + s * (1.f / 1024.f);
        atomicAdd(p.out + b * 128 + c, acc);
    }
}

// ---------------------------------------------------------------------------
extern "C" void kernel_launch(void* const* d_in, const int* in_sizes, int n_in,
                              void* d_out, int out_size, void* d_ws, size_t ws_size,
                              hipStream_t stream) {
    P p;
    p.z0   = (const float*)d_in[0];
    p.ei   = (const int*)d_in[1];
    p.attr = (const float*)d_in[2];
    p.e_w1 = (const float*)d_in[4];
    p.e_b1 = (const float*)d_in[5];
    p.e_w2 = (const float*)d_in[6];
    p.e_b2 = (const float*)d_in[7];
    p.n_w1 = (const float*)d_in[8];
    p.n_b1 = (const float*)d_in[9];
    p.ln_g = (const float*)d_in[10];
    p.ln_b = (const float*)d_in[11];
    p.n_w2 = (const float*)d_in[12];
    p.n_b2 = (const float*)d_in[13];
    p.out  = (float*)d_out;

    const size_t H = (size_t)M_ * L_;
    float* f  = (float*)d_ws;
    p.degf = f;                           // 1024
    p.a_s  = f + 1024;                    // 8192
    p.wl   = p.a_s + 8192;                // 256
    p.vb2  = p.wl + 256;                  // 256
    p.rx   = p.vb2 + 256;                 // 8192
    p.rci  = p.rx + 8192;                 // 8192
    p.rcj  = p.rci + 8192;                // 8192
    p.rh   = p.rcj + 8192;                // 8192
    p.mx0  = p.rh + 8192;                 // 8192
    p.ofs  = (int*)(p.mx0 + 8192);        // 1056
    p.tgt_s = p.ofs + 1056;               // 8192
    p.wf    = (u16*)(p.tgt_s + 8192);     // 6*16384
    p.w_n20 = p.wf + 6 * 16384;           // 16384
    p.c0t   = p.w_n20 + 16384;            // 8192
    p.t1g   = p.c0t + 8192;               // H (fragment-major)
    p.ci1   = p.t1g + H;                  // H
    p.cj1   = p.ci1 + H;                  // H

    hipMemsetAsync(p.out, 0, 8192 * sizeof(float), stream);

    k_setup<<<20, 256, 0, stream>>>(p);
    k_node0<<<512, 256, 0, stream>>>(p);
    k_node1<<<512, 256, 0, stream>>>(p);
}

// Round 2
// 222.209 us; speedup vs baseline: 1.0975x; 1.0975x over previous
//
#include <hip/hip_runtime.h>

#define B_   64
#define NQ_  1024
#define L_   128
#define E_   8192
#define M_   (B_*NQ_)
#define LDP  136        // padded LDS row stride (shorts)
#define TILE 2176       // 16*LDP u16 per tile

typedef unsigned short u16;
typedef unsigned int   u32;
typedef unsigned long long u64;
typedef __attribute__((ext_vector_type(8))) short short8;
typedef __attribute__((ext_vector_type(4))) float floatx4;

#define WVB() __builtin_amdgcn_wave_barrier()

__device__ __forceinline__ int imax2(int a, int b) { return a > b ? a : b; }

__device__ __forceinline__ u16 f2bf(float f) {
    union { float f; u32 u; } v; v.f = f;
    return (u16)((v.u + 0x7fffu + ((v.u >> 16) & 1u)) >> 16);
}
__device__ __forceinline__ float bf2f(u16 u) {
    union { u32 u; float f; } v; v.u = ((u32)u) << 16;
    return v.f;
}
__device__ __forceinline__ floatx4 mfma16(short8 a, short8 b, floatx4 c) {
    return __builtin_amdgcn_mfma_f32_16x16x32_bf16(a, b, c, 0, 0, 0);
}
__device__ __forceinline__ short8 sfrag(const u16* t, int r0, int kb, int lane) {
    return *(const short8*)(t + (r0 + (lane & 15)) * LDP + kb * 32 + (lane >> 4) * 8);
}
// fragment-major weight fetch: coalesced 16B/lane from global (L2-hot)
__device__ __forceinline__ short8 wfrag(const u16* wf, int nt, int kb, int lane) {
    return *(const short8*)(wf + (((kb << 3) + nt) * 64 + lane) * 8);
}
__device__ __forceinline__ void frag_flush(const u16* t, u16* wf, int nt, int lane) {
#pragma unroll
    for (int kb = 0; kb < 4; ++kb)
        *(short8*)(wf + (((kb << 3) + nt) * 64 + lane) * 8) = sfrag(t, 0, kb, lane);
}
__device__ __forceinline__ short8 frag_cvt(const float* base, int r0, int ld, int kb, int lane) {
    const float* p = base + (size_t)(r0 + (lane & 15)) * ld + kb * 32 + (lane >> 4) * 8;
    short8 s;
#pragma unroll
    for (int j = 0; j < 8; ++j) s[j] = (short)f2bf(p[j]);
    return s;
}
__device__ __forceinline__ void tile_store(u16* t, const floatx4* acc, int lane) {
    int col = lane & 15, qd = lane >> 4;
#pragma unroll
    for (int nt = 0; nt < 8; ++nt)
#pragma unroll
        for (int r = 0; r < 4; ++r)
            t[(qd * 4 + r) * LDP + nt * 16 + col] = f2bf(acc[nt][r]);
}
__device__ __forceinline__ void tile_flush(const u16* t, u16* g, int lane) {
#pragma unroll
    for (int it = 0; it < 4; ++it) {
        int chunk = it * 64 + lane, row = chunk >> 4, c8 = chunk & 15;
        *(uint4*)(g + (size_t)row * 128 + c8 * 8) = *(const uint4*)(t + row * LDP + c8 * 8);
    }
}
// XCD-bijective block swizzle: all 8 sub-blocks of batch b -> XCD (b&7),
// and producer (node0) uses the SAME map so b's data is born on b's XCD L2.
// r -> (xcd=r&7, k=r>>3); b = ((k&7)<<3)|xcd; sub = k>>3; blk = b*8+sub.
__device__ __forceinline__ int blk_swz() {
    int r = blockIdx.x;
    return (((((r >> 3) & 7) << 3) | (r & 7)) << 3) + (r >> 6);
}

struct P {
    const int* ei; const float* attr; const float* z0;
    const float* e_w1; const float* e_b1; const float* e_w2; const float* e_b2;
    const float* n_w1; const float* n_b1; const float* ln_g; const float* ln_b;
    const float* n_w2; const float* n_b2;
    int* ofs; int* tgt_s; float* a_s; float* degf;
    u16* wf;        // 6 fragment-major slots: 0=Wc0 1=Wd 2=We 3=Wf 4=Wc1 5=n2_1
    u16* w_n20;     // n2_0 row-major (fin GEMV)
    float* wl; float* vb2;
    float* rx; float* rci; float* rcj; float* rh; float* mx0;
    u16* c0t; u16* t1g; u16* ci1; u16* cj1;   // t1g is fragment-major (u64/lane per (tile,nt))
    float* out;
};

// ---------------------------------------------------------------------------
// Setup, 20 blocks (unchanged):
// 0 CSR; 1-2 n2_0 cvt; 3 n2_1->frag; 4-13 product GEMMs (direct global B);
// 14 rx; 15-17 rci/rcj/rh; 18 c0; 19 vb2(vectorized)+wl+zero mx0
// ---------------------------------------------------------------------------
__global__ __launch_bounds__(256) void k_setup(P p) {
    __shared__ __align__(16) char smem[17408];
    int tid = threadIdx.x, blk = blockIdx.x;
    int lane = tid & 63, w = tid >> 6, col = lane & 15, qd = lane >> 4;

    if (blk == 0) {                               // CSR build
        __shared__ int cnt[1024];
        __shared__ int wsum[4];
        __shared__ int flag;
#pragma unroll
        for (int i = 0; i < 4; ++i) cnt[tid + i * 256] = 0;
        if (tid == 0) flag = 1;
        __syncthreads();
        if (tid < 100 && p.ei[2 * tid + 1] != 0) atomicAnd(&flag, 0);
        __syncthreads();
        int i64 = flag;
        for (int e = tid; e < E_; e += 256) {
            int s = i64 ? p.ei[2 * e] : p.ei[e];
            atomicAdd(&cnt[s], 1);
        }
        __syncthreads();
        int q0 = tid * 4;
        int c0 = cnt[q0], c1 = cnt[q0 + 1], c2 = cnt[q0 + 2], c3 = cnt[q0 + 3];
        int tsum = c0 + c1 + c2 + c3, incl = tsum;
#pragma unroll
        for (int o = 1; o < 64; o <<= 1) {
            int t = __shfl_up(incl, o, 64);
            if (lane >= o) incl += t;
        }
        if (lane == 63) wsum[w] = incl;
        __syncthreads();
        int wo = 0;
        for (int i = 0; i < w; ++i) wo += wsum[i];
        int base = wo + incl - tsum;
        p.ofs[q0] = base; p.ofs[q0 + 1] = base + c0;
        p.ofs[q0 + 2] = base + c0 + c1; p.ofs[q0 + 3] = base + c0 + c1 + c2;
        p.degf[q0] = (float)c0; p.degf[q0 + 1] = (float)c1;
        p.degf[q0 + 2] = (float)c2; p.degf[q0 + 3] = (float)c3;
        if (tid == 0) p.ofs[NQ_] = E_;
        __syncthreads();
        cnt[q0] = base; cnt[q0 + 1] = base + c0;
        cnt[q0 + 2] = base + c0 + c1; cnt[q0 + 3] = base + c0 + c1 + c2;
        __syncthreads();
        for (int e = tid; e < E_; e += 256) {
            int s = i64 ? p.ei[2 * e]        : p.ei[e];
            int t = i64 ? p.ei[2 * (E_ + e)] : p.ei[E_ + e];
            int pos = atomicAdd(&cnt[s], 1);
            p.tgt_s[pos] = t;
            p.a_s[pos]   = p.attr[e];
        }
    } else if (blk <= 2) {                        // n2_0 row-major cvt, 2 halves
        int base = (blk - 1) * 8192;
        for (int idx = tid; idx < 8192; idx += 256)
            p.w_n20[base + idx] = f2bf(p.n_w2[base + idx]);
    } else if (blk == 3) {                        // n2_1 -> fragment-major slot 5
        const float* src = p.n_w2 + 16384;
        u16* dst = p.wf + 5 * 16384;
        for (int pr = w; pr < 32; pr += 4) {      // pr = kb*8+nt
            int kb = pr >> 3, nt = pr & 7;
            const float* s = src + (nt * 16 + col) * 128 + kb * 32 + qd * 8;
            short8 v;
#pragma unroll
            for (int j = 0; j < 8; ++j) v[j] = (short)f2bf(s[j]);
            *(short8*)(dst + (pr * 64 + lane) * 8) = v;
        }
    } else if (blk <= 13) {                       // product GEMMs, direct B loads
        int g = (blk - 4) >> 1, part = (blk - 4) & 1;
        const float* Pm; const float* Q; int ldp; u16* D;
        switch (g) {
            case 0:  Pm = p.n_w1 + 128;             ldp = 256; Q = p.e_w2;         D = p.wf;             break;
            case 1:  Pm = p.n_w1 + 32768 + 128;     ldp = 256; Q = p.e_w2 + 16384; D = p.wf + 4 * 16384; break;
            case 2:  Pm = p.e_w1 + 128 * 257;       ldp = 257; Q = p.n_w2;         D = p.wf + 1 * 16384; break;
            case 3:  Pm = p.e_w1 + 128 * 257 + 128; ldp = 257; Q = p.n_w2;         D = p.wf + 2 * 16384; break;
            default: Pm = p.n_w1 + 32768;           ldp = 256; Q = p.n_w2;         D = p.wf + 3 * 16384; break;
        }
        int tile = part * 4 + w;                  // 0..7, one 16-row tile per wave
        int r0 = tile * 16;
        floatx4 acc[8] = {};
#pragma unroll
        for (int kb = 0; kb < 4; ++kb) {
            short8 a = frag_cvt(Pm, r0, ldp, kb, lane);
#pragma unroll
            for (int nt = 0; nt < 8; ++nt) {
                short8 bq;                        // B[k][n] = Q[k*128+n], coalesced
#pragma unroll
                for (int j = 0; j < 8; ++j)
                    bq[j] = (short)f2bf(Q[(kb * 32 + qd * 8 + j) * 128 + nt * 16 + col]);
                acc[nt] = mfma16(a, bq, acc[nt]);
            }
        }
        u16* slot = (u16*)smem + w * TILE;
        tile_store(slot, acc, lane); WVB();
        frag_flush(slot, D, tile, lane);
    } else if (blk == 14) {                       // rx = z0@n1a0^T + n_b1_0
        int r0 = w * 16;
        floatx4 acc[8] = {};
#pragma unroll
        for (int kb = 0; kb < 4; ++kb) {
            short8 a = frag_cvt(p.z0, r0, 128, kb, lane);
#pragma unroll
            for (int nt = 0; nt < 8; ++nt)
                acc[nt] = mfma16(a, frag_cvt(p.n_w1, nt * 16, 256, kb, lane), acc[nt]);
        }
#pragma unroll
        for (int nt = 0; nt < 8; ++nt) {
            int cg = nt * 16 + col; float bv = p.n_b1[cg];
#pragma unroll
            for (int r = 0; r < 4; ++r) p.rx[(r0 + qd * 4 + r) * 128 + cg] = acc[nt][r] + bv;
        }
    } else if (blk <= 17) {                       // rci/rcj/rh = (z0+n_b2_0)@W^T (+bias)
        int r0 = w * 16;
        const float* Wp; int ld; const float* bias; float* dst;
        if (blk == 15)      { Wp = p.e_w1 + 128 * 257;       ld = 257; bias = p.e_b1 + 128; dst = p.rci; }
        else if (blk == 16) { Wp = p.e_w1 + 128 * 257 + 128; ld = 257; bias = nullptr;      dst = p.rcj; }
        else                { Wp = p.n_w1 + 32768;           ld = 256; bias = p.n_b1 + 128; dst = p.rh;  }
        floatx4 acc[8] = {};
#pragma unroll
        for (int kb = 0; kb < 4; ++kb) {
            short8 a;
            int rr = (r0 + col) * 128, kk = kb * 32 + qd * 8;
#pragma unroll
            for (int j = 0; j < 8; ++j) a[j] = (short)f2bf(p.z0[rr + kk + j] + p.n_b2[kk + j]);
#pragma unroll
            for (int nt = 0; nt < 8; ++nt)
                acc[nt] = mfma16(a, frag_cvt(Wp, nt * 16, ld, kb, lane), acc[nt]);
        }
#pragma unroll
        for (int nt = 0; nt < 8; ++nt) {
            int cg = nt * 16 + col;
            float bv = bias ? bias[cg] : 0.0f;
#pragma unroll
            for (int r = 0; r < 4; ++r) dst[(r0 + qd * 4 + r) * 128 + cg] = acc[nt][r] + bv;
        }
    } else if (blk == 18) {                       // c0 = z0@(W1a0+W1b0)^T + e_b1_0
        int r0 = w * 16;
        floatx4 a1[8] = {};
#pragma unroll
        for (int kb = 0; kb < 4; ++kb) {
            short8 a = frag_cvt(p.z0, r0, 128, kb, lane);
#pragma unroll
            for (int nt = 0; nt < 8; ++nt) {
                a1[nt] = mfma16(a, frag_cvt(p.e_w1,       nt * 16, 257, kb, lane), a1[nt]);
                a1[nt] = mfma16(a, frag_cvt(p.e_w1 + 128, nt * 16, 257, kb, lane), a1[nt]);
            }
        }
#pragma unroll
        for (int nt = 0; nt < 8; ++nt) {
            float bv = p.e_b1[nt * 16 + col];
#pragma unroll
            for (int r = 0; r < 4; ++r) a1[nt][r] += bv;
        }
        u16* slot = (u16*)smem + w * TILE;
        tile_store(slot, a1, lane); WVB();
        tile_flush(slot, p.c0t + (size_t)r0 * 128, lane);
    } else {                                      // vb2 (vectorized) + wl + zero mx0
        int k = tid >> 7, c = tid & 127;
        const float4* wp = (const float4*)(p.n_w1 + k * 32768 + c * 256 + 128);
        const float4* bp = (const float4*)(p.e_b2 + k * 128);
        float s0 = 0.f, s1 = 0.f, s2 = 0.f, s3 = 0.f;
#pragma unroll
        for (int n4 = 0; n4 < 32; ++n4) {
            float4 a = wp[n4], bv = bp[n4];
            s0 += a.x * bv.x; s1 += a.y * bv.y; s2 += a.z * bv.z; s3 += a.w * bv.w;
        }
        p.vb2[tid] = (s0 + s1) + (s2 + s3);
        p.wl[tid]  = p.e_w1[k * 128 * 257 + c * 257 + 256];
        for (int i = tid; i < 8192; i += 256) p.mx0[i] = 0.0f;
    }
}

// ---------------------------------------------------------------------------
// node0, round-0 edge phase FUSED (no gather: S[b,q]=sum_e relu(c0[b]+a*wl0)):
// S computed per-wave straight into LDS tile -> x0 GEMM -> LN -> mx0 atomics;
// ci1 = x0@Wd + rci; cj1 = x0@We + rcj (row-major for node1 gather);
// t1 = x0@Wf + rh -> FRAGMENT-MAJOR global (8B/lane, coalesced)
// XCD-swizzled so batch b's outputs are produced on XCD (b&7) for node1.
// ---------------------------------------------------------------------------
__global__ __launch_bounds__(256, 3) void k_node0(P p) {
    __shared__ __align__(16) char smem[52224];
    u16* xt = (u16*)smem;
    u16* ob = (u16*)(smem + 34816);
    int tid = threadIdx.x, lane = tid & 63, w = tid >> 6;
    int col = lane & 15, qd = lane >> 4;
    int blk = blk_swz();
    int rowbase = blk * 128 + w * 32;
    int b = blk >> 3;

    // ---- fused round-0 edge aggregation (branchless, 4-q interleaved) ----
    {
        u32 cv = ((const u32*)p.c0t)[b * 64 + lane];
        float cx = bf2f((u16)(cv & 0xffffu)), cy = bf2f((u16)(cv >> 16));
        float2 wl2 = ((const float2*)p.wl)[lane];
        for (int qq = 0; qq < 32; qq += 4) {
            int st[4], en[4];
            float ax[4] = {}, ay[4] = {};
#pragma unroll
            for (int j = 0; j < 4; ++j) {
                int q = (rowbase + qq + j) & (NQ_ - 1);
                st[j] = p.ofs[q]; en[j] = p.ofs[q + 1];
            }
            int mx = imax2(imax2(en[0] - st[0], en[1] - st[1]),
                           imax2(en[2] - st[2], en[3] - st[3]));
            for (int k2 = 0; k2 < mx; ++k2) {
#pragma unroll
                for (int j = 0; j < 4; ++j) {
                    int idx = st[j] + k2, last = en[j] - 1;
                    int safe = idx < en[j] ? idx : (last >= 0 ? last : 0);
                    float a = p.a_s[safe];
                    float vx = fmaxf(cx + a * wl2.x, 0.f);
                    float vy = fmaxf(cy + a * wl2.y, 0.f);
                    bool v = idx < en[j];
                    ax[j] += v ? vx : 0.f;
                    ay[j] += v ? vy : 0.f;
                }
            }
#pragma unroll
            for (int j = 0; j < 4; ++j) {
                int r = qq + j;
                u32* tp = (u32*)(xt + (size_t)(w * 2 + (r >> 4)) * TILE + (r & 15) * LDP);
                tp[lane] = (u32)f2bf(ax[j]) | ((u32)f2bf(ay[j]) << 16);
            }
        }
    }
    WVB();

    floatx4 xa[2][8] = {};
#pragma unroll
    for (int kb = 0; kb < 4; ++kb) {
        short8 Bv[8];
#pragma unroll
        for (int nt = 0; nt < 8; ++nt) Bv[nt] = wfrag(p.wf, nt, kb, lane);
#pragma unroll
        for (int t = 0; t < 2; ++t) {
            short8 a = sfrag(xt + (w * 2 + t) * TILE, 0, kb, lane);
#pragma unroll
            for (int nt = 0; nt < 8; ++nt) xa[t][nt] = mfma16(a, Bv[nt], xa[t][nt]);
        }
    }
    WVB();
    float s8[8] = {};
#pragma unroll
    for (int t = 0; t < 2; ++t) {
#pragma unroll
        for (int nt = 0; nt < 8; ++nt) {
            int cg = nt * 16 + col;
            float base = p.rx[b * 128 + cg], vb = p.vb2[cg];
#pragma unroll
            for (int r = 0; r < 4; ++r) {
                int row = rowbase + t * 16 + qd * 4 + r;
                xa[t][nt][r] = fmaxf(xa[t][nt][r] + base + p.degf[row & (NQ_ - 1)] * vb, 0.f);
            }
        }
#pragma unroll
        for (int r = 0; r < 4; ++r) {
            float s = 0.f, s2 = 0.f;
#pragma unroll
            for (int nt = 0; nt < 8; ++nt) { float v = xa[t][nt][r]; s += v; s2 += v * v; }
#pragma unroll
            for (int o = 1; o < 16; o <<= 1) { s += __shfl_xor(s, o, 64); s2 += __shfl_xor(s2, o, 64); }
            float mu = s * (1.f / 128.f), var = s2 * (1.f / 128.f) - mu * mu;
            float rs = rsqrtf(var + 1e-5f);
#pragma unroll
            for (int nt = 0; nt < 8; ++nt) {
                int cg = nt * 16 + col;
                float xv = (xa[t][nt][r] - mu) * rs * p.ln_g[cg] + p.ln_b[cg];
                xa[t][nt][r] = xv;
                s8[nt] += xv;
            }
        }
        tile_store(xt + (w * 2 + t) * TILE, xa[t], lane);
    }
#pragma unroll
    for (int nt = 0; nt < 8; ++nt) {
        s8[nt] += __shfl_xor(s8[nt], 16, 64);
        s8[nt] += __shfl_xor(s8[nt], 32, 64);
    }
    if (lane < 16) {
#pragma unroll
        for (int nt = 0; nt < 8; ++nt)
            atomicAdd(p.mx0 + b * 128 + nt * 16 + lane, s8[nt]);
    }
    WVB();
#pragma unroll
    for (int ph = 0; ph < 3; ++ph) {
        const u16* wfp = p.wf + ((ph == 0) ? 1 : (ph == 1) ? 2 : 3) * 16384;
        const float* rt = (ph == 0) ? p.rci : (ph == 1) ? p.rcj : p.rh;
        floatx4 ca[2][8] = {};
#pragma unroll
        for (int kb = 0; kb < 4; ++kb) {
            short8 Bv[8];
#pragma unroll
            for (int nt = 0; nt < 8; ++nt) Bv[nt] = wfrag(wfp, nt, kb, lane);
#pragma unroll
            for (int t = 0; t < 2; ++t) {
                short8 a = sfrag(xt + (w * 2 + t) * TILE, 0, kb, lane);
#pragma unroll
                for (int nt = 0; nt < 8; ++nt) ca[t][nt] = mfma16(a, Bv[nt], ca[t][nt]);
            }
        }
#pragma unroll
        for (int t = 0; t < 2; ++t)
#pragma unroll
            for (int nt = 0; nt < 8; ++nt) {
                float rc = rt[b * 128 + nt * 16 + col];
#pragma unroll
                for (int r = 0; r < 4; ++r) ca[t][nt][r] += rc;
            }
        if (ph == 2) {                            // t1 -> fragment-major, 8B/lane
            u64* t1f = (u64*)p.t1g;
#pragma unroll
            for (int t = 0; t < 2; ++t) {
                int tile = blk * 8 + w * 2 + t;
#pragma unroll
                for (int nt = 0; nt < 8; ++nt) {
                    u32 lo = (u32)f2bf(ca[t][nt][0]) | ((u32)f2bf(ca[t][nt][1]) << 16);
                    u32 hi = (u32)f2bf(ca[t][nt][2]) | ((u32)f2bf(ca[t][nt][3]) << 16);
                    t1f[(size_t)(tile * 8 + nt) * 64 + lane] = (u64)lo | ((u64)hi << 32);
                }
            }
        } else {
            u16* dst = (ph == 0) ? p.ci1 : p.cj1;
#pragma unroll
            for (int t = 0; t < 2; ++t) {
                tile_store(ob + w * TILE, ca[t], lane);
                WVB();
                tile_flush(ob + w * TILE, dst + (size_t)(rowbase + t * 16) * 128, lane);
                WVB();
            }
        }
    }
}

// ---------------------------------------------------------------------------
// node1, round-1 edge phase FUSED (gather cj1[b,t], 8-q interleave + (t,a)
// prefetch, branchless): S -> LDS -> x1 GEMM; t1 read fragment-major;
// LN; out += mean(x1@n2_1); fin GEMV
// XCD-swizzled: batch b's cj1 slice (256KB) L2-resident on XCD (b&7).
// ---------------------------------------------------------------------------
__global__ __launch_bounds__(256, 3) void k_node1(P p) {
    __shared__ __align__(16) char smem[52224];
    u16* xt = (u16*)smem;
    u16* ob = (u16*)(smem + 34816);
    int tid = threadIdx.x, lane = tid & 63, w = tid >> 6;
    int col = lane & 15, qd = lane >> 4;
    int blk = blk_swz();
    int rowbase = blk * 128 + w * 32;
    int b = blk >> 3;

    // ---- fused round-1 edge aggregation (8 q in flight) ----
    {
        float2 wl2 = ((const float2*)(p.wl + 128))[lane];
        const u32* cip = (const u32*)p.ci1;
        const u32* cjp = (const u32*)p.cj1 + (size_t)b * NQ_ * 64;
        for (int qq = 0; qq < 32; qq += 8) {
            int st[8], en[8];
            float ax[8] = {}, ay[8] = {}, cx[8], cy[8];
#pragma unroll
            for (int j = 0; j < 8; ++j) {
                int row = rowbase + qq + j;
                u32 cv = cip[(size_t)row * 64 + lane];
                cx[j] = bf2f((u16)(cv & 0xffffu)); cy[j] = bf2f((u16)(cv >> 16));
                int q = row & (NQ_ - 1);
                st[j] = p.ofs[q]; en[j] = p.ofs[q + 1];
            }
            int mx = imax2(imax2(imax2(en[0] - st[0], en[1] - st[1]),
                                 imax2(en[2] - st[2], en[3] - st[3])),
                           imax2(imax2(en[4] - st[4], en[5] - st[5]),
                                 imax2(en[6] - st[6], en[7] - st[7])));
            int tc[8]; float ac[8];
#pragma unroll
            for (int j = 0; j < 8; ++j) {         // prefetch (t,a) for k2=0
                int last = en[j] - 1;
                int safe = st[j] < en[j] ? st[j] : (last >= 0 ? last : 0);
                tc[j] = p.tgt_s[safe]; ac[j] = p.a_s[safe];
            }
            for (int k2 = 0; k2 < mx; ++k2) {
                u32 jv[8];
#pragma unroll
                for (int j = 0; j < 8; ++j)       // 8 independent 256B gathers
                    jv[j] = cjp[(size_t)tc[j] * 64 + lane];
                int tn[8]; float an[8];
#pragma unroll
                for (int j = 0; j < 8; ++j) {     // prefetch (t,a) for k2+1
                    int idx = st[j] + k2 + 1, last = en[j] - 1;
                    int safe = idx < en[j] ? idx : (last >= 0 ? last : 0);
                    tn[j] = p.tgt_s[safe]; an[j] = p.a_s[safe];
                }
#pragma unroll
                for (int j = 0; j < 8; ++j) {
                    float vx = fmaxf(cx[j] + bf2f((u16)(jv[j] & 0xffffu)) + ac[j] * wl2.x, 0.f);
                    float vy = fmaxf(cy[j] + bf2f((u16)(jv[j] >> 16))    + ac[j] * wl2.y, 0.f);
                    bool v = st[j] + k2 < en[j];
                    ax[j] += v ? vx : 0.f;
                    ay[j] += v ? vy : 0.f;
                    tc[j] = tn[j]; ac[j] = an[j];
                }
            }
#pragma unroll
            for (int j = 0; j < 8; ++j) {
                int r = qq + j;
                u32* tp = (u32*)(xt + (size_t)(w * 2 + (r >> 4)) * TILE + (r & 15) * LDP);
                tp[lane] = (u32)f2bf(ax[j]) | ((u32)f2bf(ay[j]) << 16);
            }
        }
    }
    WVB();

    const u16* wc1 = p.wf + 4 * 16384;
    floatx4 xa[2][8] = {};
#pragma unroll
    for (int kb = 0; kb < 4; ++kb) {
        short8 Bv[8];
#pragma unroll
        for (int nt = 0; nt < 8; ++nt) Bv[nt] = wfrag(wc1, nt, kb, lane);
#pragma unroll
        for (int t = 0; t < 2; ++t) {
            short8 a = sfrag(xt + (w * 2 + t) * TILE, 0, kb, lane);
#pragma unroll
            for (int nt = 0; nt < 8; ++nt) xa[t][nt] = mfma16(a, Bv[nt], xa[t][nt]);
        }
    }
    const float* vb21 = p.vb2 + 128;
    const u64* t1f = (const u64*)p.t1g;
#pragma unroll
    for (int t = 0; t < 2; ++t) {
        int tile = blk * 8 + w * 2 + t;
#pragma unroll
        for (int nt = 0; nt < 8; ++nt) {
            int cg = nt * 16 + col;
            float vb = vb21[cg];
            u64 tv = t1f[(size_t)(tile * 8 + nt) * 64 + lane];   // coalesced 8B/lane
            float tvf[4] = { bf2f((u16)tv),         bf2f((u16)(tv >> 16)),
                             bf2f((u16)(tv >> 32)), bf2f((u16)(tv >> 48)) };
#pragma unroll
            for (int r = 0; r < 4; ++r) {
                int row = rowbase + t * 16 + qd * 4 + r;
                xa[t][nt][r] = fmaxf(xa[t][nt][r] + tvf[r] + p.degf[row & (NQ_ - 1)] * vb, 0.f);
            }
        }
#pragma unroll
        for (int r = 0; r < 4; ++r) {
            float s = 0.f, s2 = 0.f;
#pragma unroll
            for (int nt = 0; nt < 8; ++nt) { float v = xa[t][nt][r]; s += v; s2 += v * v; }
#pragma unroll
            for (int o = 1; o < 16; o <<= 1) { s += __shfl_xor(s, o, 64); s2 += __shfl_xor(s2, o, 64); }
            float mu = s * (1.f / 128.f), var = s2 * (1.f / 128.f) - mu * mu;
            float rs = rsqrtf(var + 1e-5f);
#pragma unroll
            for (int nt = 0; nt < 8; ++nt) {
                int cg = nt * 16 + col;
                xa[t][nt][r] = (xa[t][nt][r] - mu) * rs * p.ln_g[128 + cg] + p.ln_b[128 + cg];
            }
        }
    }
    // mean(x1@n2_1): per-wave sequential staging through ob slot
    const u16* n21 = p.wf + 5 * 16384;
    float s8[8] = {};
#pragma unroll
    for (int t = 0; t < 2; ++t) {
        WVB();
        tile_store(ob + w * TILE, xa[t], lane);
        WVB();
        floatx4 ma[8] = {};
#pragma unroll
        for (int kb = 0; kb < 4; ++kb) {
            short8 Bv[8];
#pragma unroll
            for (int nt = 0; nt < 8; ++nt) Bv[nt] = wfrag(n21, nt, kb, lane);
            short8 a = sfrag(ob + w * TILE, 0, kb, lane);
#pragma unroll
            for (int nt = 0; nt < 8; ++nt) ma[nt] = mfma16(a, Bv[nt], ma[nt]);
        }
#pragma unroll
        for (int nt = 0; nt < 8; ++nt)
#pragma unroll
            for (int r = 0; r < 4; ++r) s8[nt] += ma[nt][r];
    }
#pragma unroll
    for (int nt = 0; nt < 8; ++nt) {
        s8[nt] += __shfl_xor(s8[nt], 16, 64);
        s8[nt] += __shfl_xor(s8[nt], 32, 64);
    }
    if (lane < 16) {
#pragma unroll
        for (int nt = 0; nt < 8; ++nt)
            atomicAdd(p.out + b * 128 + nt * 16 + lane, s8[nt] * (1.f / 1024.f));
    }
    // fin: out[b] += z0[b] + n_b2_0 + n_b2_1 + mx0[b]@n2_0^T / 1024  (vectorized)
    if ((blk & 7) == 0 && tid < 128) {
        int c = tid;
        const float* mx = p.mx0 + b * 128;
        float s = 0.f;
#pragma unroll
        for (int k8 = 0; k8 < 16; ++k8) {
            short8 wv = *(const short8*)(p.w_n20 + c * 128 + k8 * 8);
            const float* mxp = mx + k8 * 8;
#pragma unroll
            for (int j = 0; j < 8; ++j) s += mxp[j] * bf2f((u16)wv[j]);
        }
        float acc = p.z0[b * 128 + c] + p.n_b2[c] + p.n_b2[128 + c] + s * (1.f / 1024.f);
        atomicAdd(p.out + b * 128 + c, acc);
    }
}

// ---------------------------------------------------------------------------
extern "C" void kernel_launch(void* const* d_in, const int* in_sizes, int n_in,
                              void* d_out, int out_size, void* d_ws, size_t ws_size,
                              hipStream_t stream) {
    P p;
    p.z0   = (const float*)d_in[0];
    p.ei   = (const int*)d_in[1];
    p.attr = (const float*)d_in[2];
    p.e_w1 = (const float*)d_in[4];
    p.e_b1 = (const float*)d_in[5];
    p.e_w2 = (const float*)d_in[6];
    p.e_b2 = (const float*)d_in[7];
    p.n_w1 = (const float*)d_in[8];
    p.n_b1 = (const float*)d_in[9];
    p.ln_g = (const float*)d_in[10];
    p.ln_b = (const float*)d_in[11];
    p.n_w2 = (const float*)d_in[12];
    p.n_b2 = (const float*)d_in[13];
    p.out  = (float*)d_out;

    const size_t H = (size_t)M_ * L_;
    float* f  = (float*)d_ws;
    p.degf = f;                           // 1024
    p.a_s  = f + 1024;                    // 8192
    p.wl   = p.a_s + 8192;                // 256
    p.vb2  = p.wl + 256;                  // 256
    p.rx   = p.vb2 + 256;                 // 8192
    p.rci  = p.rx + 8192;                 // 8192
    p.rcj  = p.rci + 8192;                // 8192
    p.rh   = p.rcj + 8192;                // 8192
    p.mx0  = p.rh + 8192;                 // 8192
    p.ofs  = (int*)(p.mx0 + 8192);        // 1056
    p.tgt_s = p.ofs + 1056;               // 8192
    p.wf    = (u16*)(p.tgt_s + 8192);     // 6*16384
    p.w_n20 = p.wf + 6 * 16384;           // 16384
    p.c0t   = p.w_n20 + 16384;            // 8192
    p.t1g   = p.c0t + 8192;               // H (fragment-major)
    p.ci1   = p.t1g + H;                  // H
    p.cj1   = p.ci1 + H;                  // H

    hipMemsetAsync(p.out, 0, 8192 * sizeof(float), stream);

    k_setup<<<20, 256, 0, stream>>>(p);
    k_node0<<<512, 256, 0, stream>>>(p);
    k_node1<<<512, 256, 0, stream>>>(p);
}

// Round 3
// 202.745 us; speedup vs baseline: 1.2029x; 1.0960x over previous
//
#include <hip/hip_runtime.h>

#define B_   64
#define NQ_  1024
#define L_   128
#define E_   8192
#define M_   (B_*NQ_)
#define LDP  136        // padded LDS row stride (shorts)
#define TILE 2176       // 16*LDP u16 per tile

typedef unsigned short u16;
typedef unsigned int   u32;
typedef unsigned long long u64;
typedef __attribute__((ext_vector_type(8))) short short8;
typedef __attribute__((ext_vector_type(4))) float floatx4;

#define WVB() __builtin_amdgcn_wave_barrier()

__device__ __forceinline__ int imax2(int a, int b) { return a > b ? a : b; }

__device__ __forceinline__ u16 f2bf(float f) {
    union { float f; u32 u; } v; v.f = f;
    return (u16)((v.u + 0x7fffu + ((v.u >> 16) & 1u)) >> 16);
}
__device__ __forceinline__ float bf2f(u16 u) {
    union { u32 u; float f; } v; v.u = ((u32)u) << 16;
    return v.f;
}
__device__ __forceinline__ floatx4 mfma16(short8 a, short8 b, floatx4 c) {
    return __builtin_amdgcn_mfma_f32_16x16x32_bf16(a, b, c, 0, 0, 0);
}
__device__ __forceinline__ short8 sfrag(const u16* t, int r0, int kb, int lane) {
    return *(const short8*)(t + (r0 + (lane & 15)) * LDP + kb * 32 + (lane >> 4) * 8);
}
// fragment-major weight fetch: coalesced 16B/lane from global (L2-hot)
__device__ __forceinline__ short8 wfrag(const u16* wf, int nt, int kb, int lane) {
    return *(const short8*)(wf + (((kb << 3) + nt) * 64 + lane) * 8);
}
__device__ __forceinline__ void frag_flush(const u16* t, u16* wf, int nt, int lane) {
#pragma unroll
    for (int kb = 0; kb < 4; ++kb)
        *(short8*)(wf + (((kb << 3) + nt) * 64 + lane) * 8) = sfrag(t, 0, kb, lane);
}
__device__ __forceinline__ short8 frag_cvt(const float* base, int r0, int ld, int kb, int lane) {
    const float* p = base + (size_t)(r0 + (lane & 15)) * ld + kb * 32 + (lane >> 4) * 8;
    short8 s;
#pragma unroll
    for (int j = 0; j < 8; ++j) s[j] = (short)f2bf(p[j]);
    return s;
}
__device__ __forceinline__ void tile_store(u16* t, const floatx4* acc, int lane) {
    int col = lane & 15, qd = lane >> 4;
#pragma unroll
    for (int nt = 0; nt < 8; ++nt)
#pragma unroll
        for (int r = 0; r < 4; ++r)
            t[(qd * 4 + r) * LDP + nt * 16 + col] = f2bf(acc[nt][r]);
}
__device__ __forceinline__ void tile_flush(const u16* t, u16* g, int lane) {
#pragma unroll
    for (int it = 0; it < 4; ++it) {
        int chunk = it * 64 + lane, row = chunk >> 4, c8 = chunk & 15;
        *(uint4*)(g + (size_t)row * 128 + c8 * 8) = *(const uint4*)(t + row * LDP + c8 * 8);
    }
}
// XCD-bijective swizzle for 1024 blocks: HW assigns block r to XCD r&7.
// Map so batch b only appears on XCD b&7: r -> (xcd=r&7, idx=r>>3);
// b = ((idx&7)<<3)|xcd; sub = idx>>3 (0..15); blk = b*16+sub. Bijective.
__device__ __forceinline__ int blk_swz() {
    int r = blockIdx.x;
    int b = (((r >> 3) & 7) << 3) | (r & 7);
    return b * 16 + (r >> 6);
}

struct P {
    const int* ei; const float* attr; const float* z0;
    const float* e_w1; const float* e_b1; const float* e_w2; const float* e_b2;
    const float* n_w1; const float* n_b1; const float* ln_g; const float* ln_b;
    const float* n_w2; const float* n_b2;
    int* ofs; int* tgt_s; float* a_s; float* degf;
    u16* wf;        // 6 fragment-major slots: 0=Wc0 1=Wd 2=We 3=Wf 4=Wc1 5=n2_1
    u16* w_n20;     // n2_0 row-major (fin GEMV)
    float* wl; float* vb2;
    float* rx; float* rci; float* rcj; float* rh; float* mx0;
    u16* c0t; u16* t1g; u16* ci1; u16* cj1;   // t1g fragment-major (u64/lane per (tile,nt))
    float* out;
};

// ---------------------------------------------------------------------------
// Setup, 20 blocks (unchanged):
// 0 CSR; 1-2 n2_0 cvt; 3 n2_1->frag; 4-13 product GEMMs (direct global B);
// 14 rx; 15-17 rci/rcj/rh; 18 c0; 19 vb2(vectorized)+wl+zero mx0
// ---------------------------------------------------------------------------
__global__ __launch_bounds__(256) void k_setup(P p) {
    __shared__ __align__(16) char smem[17408];
    int tid = threadIdx.x, blk = blockIdx.x;
    int lane = tid & 63, w = tid >> 6, col = lane & 15, qd = lane >> 4;

    if (blk == 0) {                               // CSR build
        __shared__ int cnt[1024];
        __shared__ int wsum[4];
        __shared__ int flag;
#pragma unroll
        for (int i = 0; i < 4; ++i) cnt[tid + i * 256] = 0;
        if (tid == 0) flag = 1;
        __syncthreads();
        if (tid < 100 && p.ei[2 * tid + 1] != 0) atomicAnd(&flag, 0);
        __syncthreads();
        int i64 = flag;
        for (int e = tid; e < E_; e += 256) {
            int s = i64 ? p.ei[2 * e] : p.ei[e];
            atomicAdd(&cnt[s], 1);
        }
        __syncthreads();
        int q0 = tid * 4;
        int c0 = cnt[q0], c1 = cnt[q0 + 1], c2 = cnt[q0 + 2], c3 = cnt[q0 + 3];
        int tsum = c0 + c1 + c2 + c3, incl = tsum;
#pragma unroll
        for (int o = 1; o < 64; o <<= 1) {
            int t = __shfl_up(incl, o, 64);
            if (lane >= o) incl += t;
        }
        if (lane == 63) wsum[w] = incl;
        __syncthreads();
        int wo = 0;
        for (int i = 0; i < w; ++i) wo += wsum[i];
        int base = wo + incl - tsum;
        p.ofs[q0] = base; p.ofs[q0 + 1] = base + c0;
        p.ofs[q0 + 2] = base + c0 + c1; p.ofs[q0 + 3] = base + c0 + c1 + c2;
        p.degf[q0] = (float)c0; p.degf[q0 + 1] = (float)c1;
        p.degf[q0 + 2] = (float)c2; p.degf[q0 + 3] = (float)c3;
        if (tid == 0) p.ofs[NQ_] = E_;
        __syncthreads();
        cnt[q0] = base; cnt[q0 + 1] = base + c0;
        cnt[q0 + 2] = base + c0 + c1; cnt[q0 + 3] = base + c0 + c1 + c2;
        __syncthreads();
        for (int e = tid; e < E_; e += 256) {
            int s = i64 ? p.ei[2 * e]        : p.ei[e];
            int t = i64 ? p.ei[2 * (E_ + e)] : p.ei[E_ + e];
            int pos = atomicAdd(&cnt[s], 1);
            p.tgt_s[pos] = t;
            p.a_s[pos]   = p.attr[e];
        }
    } else if (blk <= 2) {                        // n2_0 row-major cvt, 2 halves
        int base = (blk - 1) * 8192;
        for (int idx = tid; idx < 8192; idx += 256)
            p.w_n20[base + idx] = f2bf(p.n_w2[base + idx]);
    } else if (blk == 3) {                        // n2_1 -> fragment-major slot 5
        const float* src = p.n_w2 + 16384;
        u16* dst = p.wf + 5 * 16384;
        for (int pr = w; pr < 32; pr += 4) {      // pr = kb*8+nt
            int kb = pr >> 3, nt = pr & 7;
            const float* s = src + (nt * 16 + col) * 128 + kb * 32 + qd * 8;
            short8 v;
#pragma unroll
            for (int j = 0; j < 8; ++j) v[j] = (short)f2bf(s[j]);
            *(short8*)(dst + (pr * 64 + lane) * 8) = v;
        }
    } else if (blk <= 13) {                       // product GEMMs, direct B loads
        int g = (blk - 4) >> 1, part = (blk - 4) & 1;
        const float* Pm; const float* Q; int ldp; u16* D;
        switch (g) {
            case 0:  Pm = p.n_w1 + 128;             ldp = 256; Q = p.e_w2;         D = p.wf;             break;
            case 1:  Pm = p.n_w1 + 32768 + 128;     ldp = 256; Q = p.e_w2 + 16384; D = p.wf + 4 * 16384; break;
            case 2:  Pm = p.e_w1 + 128 * 257;       ldp = 257; Q = p.n_w2;         D = p.wf + 1 * 16384; break;
            case 3:  Pm = p.e_w1 + 128 * 257 + 128; ldp = 257; Q = p.n_w2;         D = p.wf + 2 * 16384; break;
            default: Pm = p.n_w1 + 32768;           ldp = 256; Q = p.n_w2;         D = p.wf + 3 * 16384; break;
        }
        int tile = part * 4 + w;                  // 0..7, one 16-row tile per wave
        int r0 = tile * 16;
        floatx4 acc[8] = {};
#pragma unroll
        for (int kb = 0; kb < 4; ++kb) {
            short8 a = frag_cvt(Pm, r0, ldp, kb, lane);
#pragma unroll
            for (int nt = 0; nt < 8; ++nt) {
                short8 bq;                        // B[k][n] = Q[k*128+n], coalesced
#pragma unroll
                for (int j = 0; j < 8; ++j)
                    bq[j] = (short)f2bf(Q[(kb * 32 + qd * 8 + j) * 128 + nt * 16 + col]);
                acc[nt] = mfma16(a, bq, acc[nt]);
            }
        }
        u16* slot = (u16*)smem + w * TILE;
        tile_store(slot, acc, lane); WVB();
        frag_flush(slot, D, tile, lane);
    } else if (blk == 14) {                       // rx = z0@n1a0^T + n_b1_0
        int r0 = w * 16;
        floatx4 acc[8] = {};
#pragma unroll
        for (int kb = 0; kb < 4; ++kb) {
            short8 a = frag_cvt(p.z0, r0, 128, kb, lane);
#pragma unroll
            for (int nt = 0; nt < 8; ++nt)
                acc[nt] = mfma16(a, frag_cvt(p.n_w1, nt * 16, 256, kb, lane), acc[nt]);
        }
#pragma unroll
        for (int nt = 0; nt < 8; ++nt) {
            int cg = nt * 16 + col; float bv = p.n_b1[cg];
#pragma unroll
            for (int r = 0; r < 4; ++r) p.rx[(r0 + qd * 4 + r) * 128 + cg] = acc[nt][r] + bv;
        }
    } else if (blk <= 17) {                       // rci/rcj/rh = (z0+n_b2_0)@W^T (+bias)
        int r0 = w * 16;
        const float* Wp; int ld; const float* bias; float* dst;
        if (blk == 15)      { Wp = p.e_w1 + 128 * 257;       ld = 257; bias = p.e_b1 + 128; dst = p.rci; }
        else if (blk == 16) { Wp = p.e_w1 + 128 * 257 + 128; ld = 257; bias = nullptr;      dst = p.rcj; }
        else                { Wp = p.n_w1 + 32768;           ld = 256; bias = p.n_b1 + 128; dst = p.rh;  }
        floatx4 acc[8] = {};
#pragma unroll
        for (int kb = 0; kb < 4; ++kb) {
            short8 a;
            int rr = (r0 + col) * 128, kk = kb * 32 + qd * 8;
#pragma unroll
            for (int j = 0; j < 8; ++j) a[j] = (short)f2bf(p.z0[rr + kk + j] + p.n_b2[kk + j]);
#pragma unroll
            for (int nt = 0; nt < 8; ++nt)
                acc[nt] = mfma16(a, frag_cvt(Wp, nt * 16, ld, kb, lane), acc[nt]);
        }
#pragma unroll
        for (int nt = 0; nt < 8; ++nt) {
            int cg = nt * 16 + col;
            float bv = bias ? bias[cg] : 0.0f;
#pragma unroll
            for (int r = 0; r < 4; ++r) dst[(r0 + qd * 4 + r) * 128 + cg] = acc[nt][r] + bv;
        }
    } else if (blk == 18) {                       // c0 = z0@(W1a0+W1b0)^T + e_b1_0
        int r0 = w * 16;
        floatx4 a1[8] = {};
#pragma unroll
        for (int kb = 0; kb < 4; ++kb) {
            short8 a = frag_cvt(p.z0, r0, 128, kb, lane);
#pragma unroll
            for (int nt = 0; nt < 8; ++nt) {
                a1[nt] = mfma16(a, frag_cvt(p.e_w1,       nt * 16, 257, kb, lane), a1[nt]);
                a1[nt] = mfma16(a, frag_cvt(p.e_w1 + 128, nt * 16, 257, kb, lane), a1[nt]);
            }
        }
#pragma unroll
        for (int nt = 0; nt < 8; ++nt) {
            float bv = p.e_b1[nt * 16 + col];
#pragma unroll
            for (int r = 0; r < 4; ++r) a1[nt][r] += bv;
        }
        u16* slot = (u16*)smem + w * TILE;
        tile_store(slot, a1, lane); WVB();
        tile_flush(slot, p.c0t + (size_t)r0 * 128, lane);
    } else {                                      // vb2 (vectorized) + wl + zero mx0
        int k = tid >> 7, c = tid & 127;
        const float4* wp = (const float4*)(p.n_w1 + k * 32768 + c * 256 + 128);
        const float4* bp = (const float4*)(p.e_b2 + k * 128);
        float s0 = 0.f, s1 = 0.f, s2 = 0.f, s3 = 0.f;
#pragma unroll
        for (int n4 = 0; n4 < 32; ++n4) {
            float4 a = wp[n4], bv = bp[n4];
            s0 += a.x * bv.x; s1 += a.y * bv.y; s2 += a.z * bv.z; s3 += a.w * bv.w;
        }
        p.vb2[tid] = (s0 + s1) + (s2 + s3);
        p.wl[tid]  = p.e_w1[k * 128 * 257 + c * 257 + 256];
        for (int i = tid; i < 8192; i += 256) p.mx0[i] = 0.0f;
    }
}

// ---------------------------------------------------------------------------
// node0, 1024 blocks x 4 waves x 16 rows (1 tile/wave, 4 blocks/CU co-resident):
// fused round-0 edge (no gather) -> x0 GEMM -> LN -> mx0 atomics;
// ci1/cj1 row-major; t1 fragment-major (tile = row/16). XCD-swizzled.
// ---------------------------------------------------------------------------
__global__ __launch_bounds__(256, 4) void k_node0(P p) {
    __shared__ __align__(16) char smem[34816];
    u16* xt = (u16*)smem;                  // 4 waves x 1 tile
    u16* ob = (u16*)(smem + 17408);        // 4 waves x 1 tile staging
    int tid = threadIdx.x, lane = tid & 63, w = tid >> 6;
    int col = lane & 15, qd = lane >> 4;
    int blk = blk_swz();
    int rowbase = blk * 64 + w * 16;
    int b = blk >> 4;

    // ---- fused round-0 edge aggregation (branchless, 4-q interleaved) ----
    {
        u32 cv = ((const u32*)p.c0t)[b * 64 + lane];
        float cx = bf2f((u16)(cv & 0xffffu)), cy = bf2f((u16)(cv >> 16));
        float2 wl2 = ((const float2*)p.wl)[lane];
        for (int qq = 0; qq < 16; qq += 4) {
            int st[4], en[4];
            float ax[4] = {}, ay[4] = {};
#pragma unroll
            for (int j = 0; j < 4; ++j) {
                int q = (rowbase + qq + j) & (NQ_ - 1);
                st[j] = p.ofs[q]; en[j] = p.ofs[q + 1];
            }
            int mx = imax2(imax2(en[0] - st[0], en[1] - st[1]),
                           imax2(en[2] - st[2], en[3] - st[3]));
            for (int k2 = 0; k2 < mx; ++k2) {
#pragma unroll
                for (int j = 0; j < 4; ++j) {
                    int idx = st[j] + k2, last = en[j] - 1;
                    int safe = idx < en[j] ? idx : (last >= 0 ? last : 0);
                    float a = p.a_s[safe];
                    float vx = fmaxf(cx + a * wl2.x, 0.f);
                    float vy = fmaxf(cy + a * wl2.y, 0.f);
                    bool v = idx < en[j];
                    ax[j] += v ? vx : 0.f;
                    ay[j] += v ? vy : 0.f;
                }
            }
#pragma unroll
            for (int j = 0; j < 4; ++j) {
                int r = qq + j;
                u32* tp = (u32*)(xt + (size_t)w * TILE + r * LDP);
                tp[lane] = (u32)f2bf(ax[j]) | ((u32)f2bf(ay[j]) << 16);
            }
        }
    }
    WVB();

    floatx4 xa[8] = {};
#pragma unroll
    for (int kb = 0; kb < 4; ++kb) {
        short8 a = sfrag(xt + w * TILE, 0, kb, lane);
#pragma unroll
        for (int nt = 0; nt < 8; ++nt) xa[nt] = mfma16(a, wfrag(p.wf, nt, kb, lane), xa[nt]);
    }
    WVB();
    float s8[8] = {};
#pragma unroll
    for (int nt = 0; nt < 8; ++nt) {
        int cg = nt * 16 + col;
        float base = p.rx[b * 128 + cg], vb = p.vb2[cg];
#pragma unroll
        for (int r = 0; r < 4; ++r) {
            int row = rowbase + qd * 4 + r;
            xa[nt][r] = fmaxf(xa[nt][r] + base + p.degf[row & (NQ_ - 1)] * vb, 0.f);
        }
    }
#pragma unroll
    for (int r = 0; r < 4; ++r) {
        float s = 0.f, s2 = 0.f;
#pragma unroll
        for (int nt = 0; nt < 8; ++nt) { float v = xa[nt][r]; s += v; s2 += v * v; }
#pragma unroll
        for (int o = 1; o < 16; o <<= 1) { s += __shfl_xor(s, o, 64); s2 += __shfl_xor(s2, o, 64); }
        float mu = s * (1.f / 128.f), var = s2 * (1.f / 128.f) - mu * mu;
        float rs = rsqrtf(var + 1e-5f);
#pragma unroll
        for (int nt = 0; nt < 8; ++nt) {
            int cg = nt * 16 + col;
            float xv = (xa[nt][r] - mu) * rs * p.ln_g[cg] + p.ln_b[cg];
            xa[nt][r] = xv;
            s8[nt] += xv;
        }
    }
    tile_store(xt + w * TILE, xa, lane);
#pragma unroll
    for (int nt = 0; nt < 8; ++nt) {
        s8[nt] += __shfl_xor(s8[nt], 16, 64);
        s8[nt] += __shfl_xor(s8[nt], 32, 64);
    }
    if (lane < 16) {
#pragma unroll
        for (int nt = 0; nt < 8; ++nt)
            atomicAdd(p.mx0 + b * 128 + nt * 16 + lane, s8[nt]);
    }
    WVB();
#pragma unroll
    for (int ph = 0; ph < 3; ++ph) {
        const u16* wfp = p.wf + ((ph == 0) ? 1 : (ph == 1) ? 2 : 3) * 16384;
        const float* rt = (ph == 0) ? p.rci : (ph == 1) ? p.rcj : p.rh;
        floatx4 ca[8] = {};
#pragma unroll
        for (int kb = 0; kb < 4; ++kb) {
            short8 a = sfrag(xt + w * TILE, 0, kb, lane);
#pragma unroll
            for (int nt = 0; nt < 8; ++nt) ca[nt] = mfma16(a, wfrag(wfp, nt, kb, lane), ca[nt]);
        }
#pragma unroll
        for (int nt = 0; nt < 8; ++nt) {
            float rc = rt[b * 128 + nt * 16 + col];
#pragma unroll
            for (int r = 0; r < 4; ++r) ca[nt][r] += rc;
        }
        if (ph == 2) {                            // t1 -> fragment-major, 8B/lane
            u64* t1f = (u64*)p.t1g;
            int tile = blk * 4 + w;               // = global_row/16
#pragma unroll
            for (int nt = 0; nt < 8; ++nt) {
                u32 lo = (u32)f2bf(ca[nt][0]) | ((u32)f2bf(ca[nt][1]) << 16);
                u32 hi = (u32)f2bf(ca[nt][2]) | ((u32)f2bf(ca[nt][3]) << 16);
                t1f[(size_t)(tile * 8 + nt) * 64 + lane] = (u64)lo | ((u64)hi << 32);
            }
        } else {
            u16* dst = (ph == 0) ? p.ci1 : p.cj1;
            tile_store(ob + w * TILE, ca, lane);
            WVB();
            tile_flush(ob + w * TILE, dst + (size_t)rowbase * 128, lane);
            WVB();
        }
    }
}

// ---------------------------------------------------------------------------
// node1, 1024 blocks x 4 waves x 16 rows: fused round-1 gather (8 q in
// flight + (t,a) prefetch, branchless) -> x1 GEMM; t1 fragment-major read;
// LN; out += mean(x1@n2_1); fin GEMV. XCD-swizzled (cj1[b] L2-resident).
// ---------------------------------------------------------------------------
__global__ __launch_bounds__(256, 4) void k_node1(P p) {
    __shared__ __align__(16) char smem[34816];
    u16* xt = (u16*)smem;
    u16* ob = (u16*)(smem + 17408);
    int tid = threadIdx.x, lane = tid & 63, w = tid >> 6;
    int col = lane & 15, qd = lane >> 4;
    int blk = blk_swz();
    int rowbase = blk * 64 + w * 16;
    int b = blk >> 4;

    // ---- fused round-1 edge aggregation (8 q in flight) ----
    {
        float2 wl2 = ((const float2*)(p.wl + 128))[lane];
        const u32* cip = (const u32*)p.ci1;
        const u32* cjp = (const u32*)p.cj1 + (size_t)b * NQ_ * 64;
        for (int qq = 0; qq < 16; qq += 8) {
            int st[8], en[8];
            float ax[8] = {}, ay[8] = {}, cx[8], cy[8];
#pragma unroll
            for (int j = 0; j < 8; ++j) {
                int row = rowbase + qq + j;
                u32 cv = cip[(size_t)row * 64 + lane];
                cx[j] = bf2f((u16)(cv & 0xffffu)); cy[j] = bf2f((u16)(cv >> 16));
                int q = row & (NQ_ - 1);
                st[j] = p.ofs[q]; en[j] = p.ofs[q + 1];
            }
            int mx = imax2(imax2(imax2(en[0] - st[0], en[1] - st[1]),
                                 imax2(en[2] - st[2], en[3] - st[3])),
                           imax2(imax2(en[4] - st[4], en[5] - st[5]),
                                 imax2(en[6] - st[6], en[7] - st[7])));
            int tc[8]; float ac[8];
#pragma unroll
            for (int j = 0; j < 8; ++j) {         // prefetch (t,a) for k2=0
                int last = en[j] - 1;
                int safe = st[j] < en[j] ? st[j] : (last >= 0 ? last : 0);
                tc[j] = p.tgt_s[safe]; ac[j] = p.a_s[safe];
            }
            for (int k2 = 0; k2 < mx; ++k2) {
                u32 jv[8];
#pragma unroll
                for (int j = 0; j < 8; ++j)       // 8 independent 256B gathers
                    jv[j] = cjp[(size_t)tc[j] * 64 + lane];
                int tn[8]; float an[8];
#pragma unroll
                for (int j = 0; j < 8; ++j) {     // prefetch (t,a) for k2+1
                    int idx = st[j] + k2 + 1, last = en[j] - 1;
                    int safe = idx < en[j] ? idx : (last >= 0 ? last : 0);
                    tn[j] = p.tgt_s[safe]; an[j] = p.a_s[safe];
                }
#pragma unroll
                for (int j = 0; j < 8; ++j) {
                    float vx = fmaxf(cx[j] + bf2f((u16)(jv[j] & 0xffffu)) + ac[j] * wl2.x, 0.f);
                    float vy = fmaxf(cy[j] + bf2f((u16)(jv[j] >> 16))    + ac[j] * wl2.y, 0.f);
                    bool v = st[j] + k2 < en[j];
                    ax[j] += v ? vx : 0.f;
                    ay[j] += v ? vy : 0.f;
                    tc[j] = tn[j]; ac[j] = an[j];
                }
            }
#pragma unroll
            for (int j = 0; j < 8; ++j) {
                int r = qq + j;
                u32* tp = (u32*)(xt + (size_t)w * TILE + r * LDP);
                tp[lane] = (u32)f2bf(ax[j]) | ((u32)f2bf(ay[j]) << 16);
            }
        }
    }
    WVB();

    const u16* wc1 = p.wf + 4 * 16384;
    floatx4 xa[8] = {};
#pragma unroll
    for (int kb = 0; kb < 4; ++kb) {
        short8 a = sfrag(xt + w * TILE, 0, kb, lane);
#pragma unroll
        for (int nt = 0; nt < 8; ++nt) xa[nt] = mfma16(a, wfrag(wc1, nt, kb, lane), xa[nt]);
    }
    const float* vb21 = p.vb2 + 128;
    const u64* t1f = (const u64*)p.t1g;
    int tile = blk * 4 + w;                       // = global_row/16
#pragma unroll
    for (int nt = 0; nt < 8; ++nt) {
        int cg = nt * 16 + col;
        float vb = vb21[cg];
        u64 tv = t1f[(size_t)(tile * 8 + nt) * 64 + lane];   // coalesced 8B/lane
        float tvf[4] = { bf2f((u16)tv),         bf2f((u16)(tv >> 16)),
                         bf2f((u16)(tv >> 32)), bf2f((u16)(tv >> 48)) };
#pragma unroll
        for (int r = 0; r < 4; ++r) {
            int row = rowbase + qd * 4 + r;
            xa[nt][r] = fmaxf(xa[nt][r] + tvf[r] + p.degf[row & (NQ_ - 1)] * vb, 0.f);
        }
    }
#pragma unroll
    for (int r = 0; r < 4; ++r) {
        float s = 0.f, s2 = 0.f;
#pragma unroll
        for (int nt = 0; nt < 8; ++nt) { float v = xa[nt][r]; s += v; s2 += v * v; }
#pragma unroll
        for (int o = 1; o < 16; o <<= 1) { s += __shfl_xor(s, o, 64); s2 += __shfl_xor(s2, o, 64); }
        float mu = s * (1.f / 128.f), var = s2 * (1.f / 128.f) - mu * mu;
        float rs = rsqrtf(var + 1e-5f);
#pragma unroll
        for (int nt = 0; nt < 8; ++nt) {
            int cg = nt * 16 + col;
            xa[nt][r] = (xa[nt][r] - mu) * rs * p.ln_g[128 + cg] + p.ln_b[128 + cg];
        }
    }
    // mean(x1@n2_1): per-wave staging through ob slot
    const u16* n21 = p.wf + 5 * 16384;
    float s8[8] = {};
    tile_store(ob + w * TILE, xa, lane);
    WVB();
    {
        floatx4 ma[8] = {};
#pragma unroll
        for (int kb = 0; kb < 4; ++kb) {
            short8 a = sfrag(ob + w * TILE, 0, kb, lane);
#pragma unroll
            for (int nt = 0; nt < 8; ++nt) ma[nt] = mfma16(a, wfrag(n21, nt, kb, lane), ma[nt]);
        }
#pragma unroll
        for (int nt = 0; nt < 8; ++nt)
#pragma unroll
            for (int r = 0; r < 4; ++r) s8[nt] += ma[nt][r];
    }
#pragma unroll
    for (int nt = 0; nt < 8; ++nt) {
        s8[nt] += __shfl_xor(s8[nt], 16, 64);
        s8[nt] += __shfl_xor(s8[nt], 32, 64);
    }
    if (lane < 16) {
#pragma unroll
        for (int nt = 0; nt < 8; ++nt)
            atomicAdd(p.out + b * 128 + nt * 16 + lane, s8[nt] * (1.f / 1024.f));
    }
    // fin: out[b] += z0[b] + n_b2_0 + n_b2_1 + mx0[b]@n2_0^T / 1024  (vectorized)
    if ((blk & 15) == 0 && tid < 128) {
        int c = tid;
        const float* mx = p.mx0 + b * 128;
        float s = 0.f;
#pragma unroll
        for (int k8 = 0; k8 < 16; ++k8) {
            short8 wv = *(const short8*)(p.w_n20 + c * 128 + k8 * 8);
            const float* mxp = mx + k8 * 8;
#pragma unroll
            for (int j = 0; j < 8; ++j) s += mxp[j] * bf2f((u16)wv[j]);
        }
        float acc = p.z0[b * 128 + c] + p.n_b2[c] + p.n_b2[128 + c] + s * (1.f / 1024.f);
        atomicAdd(p.out + b * 128 + c, acc);
    }
}

// ---------------------------------------------------------------------------
extern "C" void kernel_launch(void* const* d_in, const int* in_sizes, int n_in,
                              void* d_out, int out_size, void* d_ws, size_t ws_size,
                              hipStream_t stream) {
    P p;
    p.z0   = (const float*)d_in[0];
    p.ei   = (const int*)d_in[1];
    p.attr = (const float*)d_in[2];
    p.e_w1 = (const float*)d_in[4];
    p.e_b1 = (const float*)d_in[5];
    p.e_w2 = (const float*)d_in[6];
    p.e_b2 = (const float*)d_in[7];
    p.n_w1 = (const float*)d_in[8];
    p.n_b1 = (const float*)d_in[9];
    p.ln_g = (const float*)d_in[10];
    p.ln_b = (const float*)d_in[11];
    p.n_w2 = (const float*)d_in[12];
    p.n_b2 = (const float*)d_in[13];
    p.out  = (float*)d_out;

    const size_t H = (size_t)M_ * L_;
    float* f  = (float*)d_ws;
    p.degf = f;                           // 1024
    p.a_s  = f + 1024;                    // 8192
    p.wl   = p.a_s + 8192;                // 256
    p.vb2  = p.wl + 256;                  // 256
    p.rx   = p.vb2 + 256;                 // 8192
    p.rci  = p.rx + 8192;                 // 8192
    p.rcj  = p.rci + 8192;                // 8192
    p.rh   = p.rcj + 8192;                // 8192
    p.mx0  = p.rh + 8192;                 // 8192
    p.ofs  = (int*)(p.mx0 + 8192);        // 1056
    p.tgt_s = p.ofs + 1056;               // 8192
    p.wf    = (u16*)(p.tgt_s + 8192);     // 6*16384
    p.w_n20 = p.wf + 6 * 16384;           // 16384
    p.c0t   = p.w_n20 + 16384;            // 8192
    p.t1g   = p.c0t + 8192;               // H (fragment-major)
    p.ci1   = p.t1g + H;                  // H
    p.cj1   = p.ci1 + H;                  // H

    hipMemsetAsync(p.out, 0, 8192 * sizeof(float), stream);

    k_setup<<<20, 256, 0, stream>>>(p);
    k_node0<<<1024, 256, 0, stream>>>(p);
    k_node1<<<1024, 256, 0, stream>>>(p);
}

// Round 4
// 191.963 us; speedup vs baseline: 1.2705x; 1.0562x over previous
//
#include <hip/hip_runtime.h>

#define B_   64
#define NQ_  1024
#define L_   128
#define E_   8192
#define M_   (B_*NQ_)
#define LDP  136        // padded LDS row stride (shorts)
#define TILE 2176       // 16*LDP u16 per tile

typedef unsigned short u16;
typedef unsigned int   u32;
typedef unsigned long long u64;
typedef __attribute__((ext_vector_type(8))) short short8;
typedef __attribute__((ext_vector_type(4))) float floatx4;

#define WVB() __builtin_amdgcn_wave_barrier()

__device__ __forceinline__ int imax2(int a, int b) { return a > b ? a : b; }
__device__ __forceinline__ int imin2(int a, int b) { return a < b ? a : b; }

__device__ __forceinline__ u16 f2bf(float f) {
    union { float f; u32 u; } v; v.f = f;
    return (u16)((v.u + 0x7fffu + ((v.u >> 16) & 1u)) >> 16);
}
__device__ __forceinline__ float bf2f(u16 u) {
    union { u32 u; float f; } v; v.u = ((u32)u) << 16;
    return v.f;
}
__device__ __forceinline__ float bf2f_lo(u32 jv) { return __uint_as_float(jv << 16); }
__device__ __forceinline__ float bf2f_hi(u32 jv) { return __uint_as_float(jv & 0xffff0000u); }
__device__ __forceinline__ floatx4 mfma16(short8 a, short8 b, floatx4 c) {
    return __builtin_amdgcn_mfma_f32_16x16x32_bf16(a, b, c, 0, 0, 0);
}
__device__ __forceinline__ short8 sfrag(const u16* t, int r0, int kb, int lane) {
    return *(const short8*)(t + (r0 + (lane & 15)) * LDP + kb * 32 + (lane >> 4) * 8);
}
// fragment-major weight fetch: coalesced 16B/lane from global (L2-hot)
__device__ __forceinline__ short8 wfrag(const u16* wf, int nt, int kb, int lane) {
    return *(const short8*)(wf + (((kb << 3) + nt) * 64 + lane) * 8);
}
__device__ __forceinline__ void frag_flush(const u16* t, u16* wf, int nt, int lane) {
#pragma unroll
    for (int kb = 0; kb < 4; ++kb)
        *(short8*)(wf + (((kb << 3) + nt) * 64 + lane) * 8) = sfrag(t, 0, kb, lane);
}
__device__ __forceinline__ short8 frag_cvt(const float* base, int r0, int ld, int kb, int lane) {
    const float* p = base + (size_t)(r0 + (lane & 15)) * ld + kb * 32 + (lane >> 4) * 8;
    short8 s;
#pragma unroll
    for (int j = 0; j < 8; ++j) s[j] = (short)f2bf(p[j]);
    return s;
}
__device__ __forceinline__ void tile_store(u16* t, const floatx4* acc, int lane) {
    int col = lane & 15, qd = lane >> 4;
#pragma unroll
    for (int nt = 0; nt < 8; ++nt)
#pragma unroll
        for (int r = 0; r < 4; ++r)
            t[(qd * 4 + r) * LDP + nt * 16 + col] = f2bf(acc[nt][r]);
}
__device__ __forceinline__ void tile_flush(const u16* t, u16* g, int lane) {
#pragma unroll
    for (int it = 0; it < 4; ++it) {
        int chunk = it * 64 + lane, row = chunk >> 4, c8 = chunk & 15;
        *(uint4*)(g + (size_t)row * 128 + c8 * 8) = *(const uint4*)(t + row * LDP + c8 * 8);
    }
}
// XCD-bijective swizzle for 1024 blocks: HW assigns block r to XCD r&7.
// Map so batch b only appears on XCD b&7.
__device__ __forceinline__ int blk_swz() {
    int r = blockIdx.x;
    int b = (((r >> 3) & 7) << 3) | (r & 7);
    return b * 16 + (r >> 6);
}

struct P {
    const int* ei; const float* attr; const float* z0;
    const float* e_w1; const float* e_b1; const float* e_w2; const float* e_b2;
    const float* n_w1; const float* n_b1; const float* ln_g; const float* ln_b;
    const float* n_w2; const float* n_b2;
    int* ofs; int2* ta; int* perm; float* degf;
    u16* wf;        // 6 fragment-major slots: 0=Wc0 1=Wd 2=We 3=Wf 4=Wc1 5=n2_1
    u16* w_n20;     // n2_0 row-major (fin GEMV)
    float* wl; float* vb2;
    float* rx; float* rci; float* rcj; float* rh; float* mx0;
    u16* c0t; u16* t1g; u16* ci1; u16* cj1;   // t1g fragment-major
    float* out;
};

// ---------------------------------------------------------------------------
// Setup, 20 blocks:
// 0 CSR + degree counting-sort perm; 1-2 n2_0 cvt; 3 n2_1->frag;
// 4-13 product GEMMs; 14 rx; 15-17 rci/rcj/rh; 18 c0; 19 vb2+wl+zero mx0
// ---------------------------------------------------------------------------
__global__ __launch_bounds__(256) void k_setup(P p) {
    __shared__ __align__(16) char smem[17408];
    int tid = threadIdx.x, blk = blockIdx.x;
    int lane = tid & 63, w = tid >> 6, col = lane & 15, qd = lane >> 4;

    if (blk == 0) {                               // CSR build + degree sort
        __shared__ int cnt[1024];
        __shared__ int wsum[4];
        __shared__ int dh[64];                    // degree histogram
        __shared__ int db[64];                    // exclusive bases (scatter)
        __shared__ int flag;
#pragma unroll
        for (int i = 0; i < 4; ++i) cnt[tid + i * 256] = 0;
        if (tid < 64) dh[tid] = 0;
        if (tid == 0) flag = 1;
        __syncthreads();
        if (tid < 100 && p.ei[2 * tid + 1] != 0) atomicAnd(&flag, 0);
        __syncthreads();
        int i64 = flag;
        for (int e = tid; e < E_; e += 256) {
            int s = i64 ? p.ei[2 * e] : p.ei[e];
            atomicAdd(&cnt[s], 1);
        }
        __syncthreads();
        int q0 = tid * 4;
        int c0 = cnt[q0], c1 = cnt[q0 + 1], c2 = cnt[q0 + 2], c3 = cnt[q0 + 3];
        int tsum = c0 + c1 + c2 + c3, incl = tsum;
#pragma unroll
        for (int o = 1; o < 64; o <<= 1) {
            int t = __shfl_up(incl, o, 64);
            if (lane >= o) incl += t;
        }
        if (lane == 63) wsum[w] = incl;
        // degree histogram
        atomicAdd(&dh[imin2(c0, 63)], 1); atomicAdd(&dh[imin2(c1, 63)], 1);
        atomicAdd(&dh[imin2(c2, 63)], 1); atomicAdd(&dh[imin2(c3, 63)], 1);
        __syncthreads();
        int wo = 0;
        for (int i = 0; i < w; ++i) wo += wsum[i];
        int base = wo + incl - tsum;
        p.ofs[q0] = base; p.ofs[q0 + 1] = base + c0;
        p.ofs[q0 + 2] = base + c0 + c1; p.ofs[q0 + 3] = base + c0 + c1 + c2;
        p.degf[q0] = (float)c0; p.degf[q0 + 1] = (float)c1;
        p.degf[q0 + 2] = (float)c2; p.degf[q0 + 3] = (float)c3;
        if (tid == 0) p.ofs[NQ_] = E_;
        __syncthreads();
        cnt[q0] = base; cnt[q0 + 1] = base + c0;
        cnt[q0 + 2] = base + c0 + c1; cnt[q0 + 3] = base + c0 + c1 + c2;
        if (tid < 64) {                           // exclusive scan of 64 bins
            int v = dh[tid], inc = v;
#pragma unroll
            for (int o = 1; o < 64; o <<= 1) {
                int t = __shfl_up(inc, o, 64);
                if (tid >= o) inc += t;
            }
            db[tid] = inc - v;
        }
        __syncthreads();
        for (int e = tid; e < E_; e += 256) {
            int s = i64 ? p.ei[2 * e]        : p.ei[e];
            int t = i64 ? p.ei[2 * (E_ + e)] : p.ei[E_ + e];
            int pos = atomicAdd(&cnt[s], 1);
            p.ta[pos] = make_int2(t << 6, __float_as_int(p.attr[e]));
        }
        // perm scatter: sorted-position -> q (counting sort, arbitrary in-bin order)
        p.perm[atomicAdd(&db[imin2(c0, 63)], 1)] = q0;
        p.perm[atomicAdd(&db[imin2(c1, 63)], 1)] = q0 + 1;
        p.perm[atomicAdd(&db[imin2(c2, 63)], 1)] = q0 + 2;
        p.perm[atomicAdd(&db[imin2(c3, 63)], 1)] = q0 + 3;
        if (tid == 0) p.ta[E_] = make_int2(0, 0);   // pad slot for lean prefetch
    } else if (blk <= 2) {                        // n2_0 row-major cvt, 2 halves
        int base = (blk - 1) * 8192;
        for (int idx = tid; idx < 8192; idx += 256)
            p.w_n20[base + idx] = f2bf(p.n_w2[base + idx]);
    } else if (blk == 3) {                        // n2_1 -> fragment-major slot 5
        const float* src = p.n_w2 + 16384;
        u16* dst = p.wf + 5 * 16384;
        for (int pr = w; pr < 32; pr += 4) {      // pr = kb*8+nt
            int kb = pr >> 3, nt = pr & 7;
            const float* s = src + (nt * 16 + col) * 128 + kb * 32 + qd * 8;
            short8 v;
#pragma unroll
            for (int j = 0; j < 8; ++j) v[j] = (short)f2bf(s[j]);
            *(short8*)(dst + (pr * 64 + lane) * 8) = v;
        }
    } else if (blk <= 13) {                       // product GEMMs, direct B loads
        int g = (blk - 4) >> 1, part = (blk - 4) & 1;
        const float* Pm; const float* Q; int ldp; u16* D;
        switch (g) {
            case 0:  Pm = p.n_w1 + 128;             ldp = 256; Q = p.e_w2;         D = p.wf;             break;
            case 1:  Pm = p.n_w1 + 32768 + 128;     ldp = 256; Q = p.e_w2 + 16384; D = p.wf + 4 * 16384; break;
            case 2:  Pm = p.e_w1 + 128 * 257;       ldp = 257; Q = p.n_w2;         D = p.wf + 1 * 16384; break;
            case 3:  Pm = p.e_w1 + 128 * 257 + 128; ldp = 257; Q = p.n_w2;         D = p.wf + 2 * 16384; break;
            default: Pm = p.n_w1 + 32768;           ldp = 256; Q = p.n_w2;         D = p.wf + 3 * 16384; break;
        }
        int tile = part * 4 + w;                  // 0..7, one 16-row tile per wave
        int r0 = tile * 16;
        floatx4 acc[8] = {};
#pragma unroll
        for (int kb = 0; kb < 4; ++kb) {
            short8 a = frag_cvt(Pm, r0, ldp, kb, lane);
#pragma unroll
            for (int nt = 0; nt < 8; ++nt) {
                short8 bq;                        // B[k][n] = Q[k*128+n], coalesced
#pragma unroll
                for (int j = 0; j < 8; ++j)
                    bq[j] = (short)f2bf(Q[(kb * 32 + qd * 8 + j) * 128 + nt * 16 + col]);
                acc[nt] = mfma16(a, bq, acc[nt]);
            }
        }
        u16* slot = (u16*)smem + w * TILE;
        tile_store(slot, acc, lane); WVB();
        frag_flush(slot, D, tile, lane);
    } else if (blk == 14) {                       // rx = z0@n1a0^T + n_b1_0
        int r0 = w * 16;
        floatx4 acc[8] = {};
#pragma unroll
        for (int kb = 0; kb < 4; ++kb) {
            short8 a = frag_cvt(p.z0, r0, 128, kb, lane);
#pragma unroll
            for (int nt = 0; nt < 8; ++nt)
                acc[nt] = mfma16(a, frag_cvt(p.n_w1, nt * 16, 256, kb, lane), acc[nt]);
        }
#pragma unroll
        for (int nt = 0; nt < 8; ++nt) {
            int cg = nt * 16 + col; float bv = p.n_b1[cg];
#pragma unroll
            for (int r = 0; r < 4; ++r) p.rx[(r0 + qd * 4 + r) * 128 + cg] = acc[nt][r] + bv;
        }
    } else if (blk <= 17) {                       // rci/rcj/rh = (z0+n_b2_0)@W^T (+bias)
        int r0 = w * 16;
        const float* Wp; int ld; const float* bias; float* dst;
        if (blk == 15)      { Wp = p.e_w1 + 128 * 257;       ld = 257; bias = p.e_b1 + 128; dst = p.rci; }
        else if (blk == 16) { Wp = p.e_w1 + 128 * 257 + 128; ld = 257; bias = nullptr;      dst = p.rcj; }
        else                { Wp = p.n_w1 + 32768;           ld = 256; bias = p.n_b1 + 128; dst = p.rh;  }
        floatx4 acc[8] = {};
#pragma unroll
        for (int kb = 0; kb < 4; ++kb) {
            short8 a;
            int rr = (r0 + col) * 128, kk = kb * 32 + qd * 8;
#pragma unroll
            for (int j = 0; j < 8; ++j) a[j] = (short)f2bf(p.z0[rr + kk + j] + p.n_b2[kk + j]);
#pragma unroll
            for (int nt = 0; nt < 8; ++nt)
                acc[nt] = mfma16(a, frag_cvt(Wp, nt * 16, ld, kb, lane), acc[nt]);
        }
#pragma unroll
        for (int nt = 0; nt < 8; ++nt) {
            int cg = nt * 16 + col;
            float bv = bias ? bias[cg] : 0.0f;
#pragma unroll
            for (int r = 0; r < 4; ++r) dst[(r0 + qd * 4 + r) * 128 + cg] = acc[nt][r] + bv;
        }
    } else if (blk == 18) {                       // c0 = z0@(W1a0+W1b0)^T + e_b1_0
        int r0 = w * 16;
        floatx4 a1[8] = {};
#pragma unroll
        for (int kb = 0; kb < 4; ++kb) {
            short8 a = frag_cvt(p.z0, r0, 128, kb, lane);
#pragma unroll
            for (int nt = 0; nt < 8; ++nt) {
                a1[nt] = mfma16(a, frag_cvt(p.e_w1,       nt * 16, 257, kb, lane), a1[nt]);
                a1[nt] = mfma16(a, frag_cvt(p.e_w1 + 128, nt * 16, 257, kb, lane), a1[nt]);
            }
        }
#pragma unroll
        for (int nt = 0; nt < 8; ++nt) {
            float bv = p.e_b1[nt * 16 + col];
#pragma unroll
            for (int r = 0; r < 4; ++r) a1[nt][r] += bv;
        }
        u16* slot = (u16*)smem + w * TILE;
        tile_store(slot, a1, lane); WVB();
        tile_flush(slot, p.c0t + (size_t)r0 * 128, lane);
    } else {                                      // vb2 (vectorized) + wl + zero mx0
        int k = tid >> 7, c = tid & 127;
        const float4* wp = (const float4*)(p.n_w1 + k * 32768 + c * 256 + 128);
        const float4* bp = (const float4*)(p.e_b2 + k * 128);
        float s0 = 0.f, s1 = 0.f, s2 = 0.f, s3 = 0.f;
#pragma unroll
        for (int n4 = 0; n4 < 32; ++n4) {
            float4 a = wp[n4], bv = bp[n4];
            s0 += a.x * bv.x; s1 += a.y * bv.y; s2 += a.z * bv.z; s3 += a.w * bv.w;
        }
        p.vb2[tid] = (s0 + s1) + (s2 + s3);
        p.wl[tid]  = p.e_w1[k * 128 * 257 + c * 257 + 256];
        for (int i = tid; i < 8192; i += 256) p.mx0[i] = 0.0f;
    }
}

// Per-wave sorted-group setup: wave W handles sorted groups (W, 127-W).
// qmap (LDS, 16 ints/wave) gives logical q per physical tile row.
__device__ __forceinline__ void load_qmap(int* qmap, const int* perm,
                                          int blk, int w, int lane) {
    int W = (blk & 15) * 4 + w;
    int g0 = W, g1 = 127 - W;
    if (lane < 16)
        qmap[w * 16 + lane] = perm[lane < 8 ? g0 * 8 + lane : g1 * 8 + lane - 8];
    WVB();
}

// ---------------------------------------------------------------------------
// node0, 1024 blocks x 4 waves x 16 rows (sorted-row assignment):
// fused round-0 edge (no gather, lean/tail) -> x0 GEMM -> LN -> mx0 atomics;
// ci1 physical rows; cj1 scattered to ORIGINAL q; t1 fragment-major (physical).
// ---------------------------------------------------------------------------
__global__ __launch_bounds__(256, 4) void k_node0(P p) {
    __shared__ __align__(16) char smem[35072];
    u16* xt = (u16*)smem;                  // 4 waves x 1 tile
    u16* ob = (u16*)(smem + 17408);        // 4 waves x 1 tile staging
    int* qmap = (int*)(smem + 34816);      // 4 waves x 16 ints
    int tid = threadIdx.x, lane = tid & 63, w = tid >> 6;
    int col = lane & 15, qd = lane >> 4;
    int blk = blk_swz();
    int rowbase = blk * 64 + w * 16;
    int b = blk >> 4;
    load_qmap(qmap, p.perm, blk, w, lane);

    // ---- fused round-0 edge aggregation (sorted, lean/tail, 8-row groups) ----
    {
        u32 cv = ((const u32*)p.c0t)[b * 64 + lane];
        float cx = bf2f((u16)(cv & 0xffffu)), cy = bf2f((u16)(cv >> 16));
        float2 wl2 = ((const float2*)p.wl)[lane];
        const int* tay = (const int*)p.ta;        // .y at 2*idx+1
        for (int g2 = 0; g2 < 2; ++g2) {
            int st[8], en[8];
            float ax[8] = {}, ay[8] = {};
#pragma unroll
            for (int j = 0; j < 8; ++j) {
                int q = qmap[w * 16 + g2 * 8 + j];
                st[j] = p.ofs[q]; en[j] = p.ofs[q + 1];
            }
            int mn = en[0] - st[0], mx = mn;
#pragma unroll
            for (int j = 1; j < 8; ++j) {
                mn = imin2(mn, en[j] - st[j]); mx = imax2(mx, en[j] - st[j]);
            }
            float ac[8];
#pragma unroll
            for (int j = 0; j < 8; ++j) {         // clamped init prefetch
                int last = en[j] - 1;
                int safe = st[j] < en[j] ? st[j] : (last >= 0 ? last : 0);
                ac[j] = __int_as_float(tay[2 * safe + 1]);
            }
            for (int k2 = 0; k2 < mn; ++k2) {     // lean: no masks, no clamps
                float an[8];
#pragma unroll
                for (int j = 0; j < 8; ++j) an[j] = __int_as_float(tay[2 * (st[j] + k2 + 1) + 1]);
#pragma unroll
                for (int j = 0; j < 8; ++j) {
                    ax[j] += fmaxf(cx + ac[j] * wl2.x, 0.f);
                    ay[j] += fmaxf(cy + ac[j] * wl2.y, 0.f);
                    ac[j] = an[j];
                }
            }
            for (int k2 = mn; k2 < mx; ++k2) {    // masked tail
                float an[8];
#pragma unroll
                for (int j = 0; j < 8; ++j) {
                    int idx = st[j] + k2 + 1, last = en[j] - 1;
                    int safe = idx < en[j] ? idx : (last >= 0 ? last : 0);
                    an[j] = __int_as_float(tay[2 * safe + 1]);
                }
#pragma unroll
                for (int j = 0; j < 8; ++j) {
                    bool v = st[j] + k2 < en[j];
                    ax[j] += v ? fmaxf(cx + ac[j] * wl2.x, 0.f) : 0.f;
                    ay[j] += v ? fmaxf(cy + ac[j] * wl2.y, 0.f) : 0.f;
                    ac[j] = an[j];
                }
            }
#pragma unroll
            for (int j = 0; j < 8; ++j) {
                int r = g2 * 8 + j;
                u32* tp = (u32*)(xt + (size_t)w * TILE + r * LDP);
                tp[lane] = (u32)f2bf(ax[j]) | ((u32)f2bf(ay[j]) << 16);
            }
        }
    }
    WVB();

    floatx4 xa[8] = {};
#pragma unroll
    for (int kb = 0; kb < 4; ++kb) {
        short8 a = sfrag(xt + w * TILE, 0, kb, lane);
#pragma unroll
        for (int nt = 0; nt < 8; ++nt) xa[nt] = mfma16(a, wfrag(p.wf, nt, kb, lane), xa[nt]);
    }
    WVB();
    float s8[8] = {};
#pragma unroll
    for (int nt = 0; nt < 8; ++nt) {
        int cg = nt * 16 + col;
        float base = p.rx[b * 128 + cg], vb = p.vb2[cg];
#pragma unroll
        for (int r = 0; r < 4; ++r) {
            int q = qmap[w * 16 + qd * 4 + r];
            xa[nt][r] = fmaxf(xa[nt][r] + base + p.degf[q] * vb, 0.f);
        }
    }
#pragma unroll
    for (int r = 0; r < 4; ++r) {
        float s = 0.f, s2 = 0.f;
#pragma unroll
        for (int nt = 0; nt < 8; ++nt) { float v = xa[nt][r]; s += v; s2 += v * v; }
#pragma unroll
        for (int o = 1; o < 16; o <<= 1) { s += __shfl_xor(s, o, 64); s2 += __shfl_xor(s2, o, 64); }
        float mu = s * (1.f / 128.f), var = s2 * (1.f / 128.f) - mu * mu;
        float rs = rsqrtf(var + 1e-5f);
#pragma unroll
        for (int nt = 0; nt < 8; ++nt) {
            int cg = nt * 16 + col;
            float xv = (xa[nt][r] - mu) * rs * p.ln_g[cg] + p.ln_b[cg];
            xa[nt][r] = xv;
            s8[nt] += xv;
        }
    }
    tile_store(xt + w * TILE, xa, lane);
#pragma unroll
    for (int nt = 0; nt < 8; ++nt) {
        s8[nt] += __shfl_xor(s8[nt], 16, 64);
        s8[nt] += __shfl_xor(s8[nt], 32, 64);
    }
    if (lane < 16) {
#pragma unroll
        for (int nt = 0; nt < 8; ++nt)
            atomicAdd(p.mx0 + b * 128 + nt * 16 + lane, s8[nt]);
    }
    WVB();
#pragma unroll
    for (int ph = 0; ph < 3; ++ph) {
        const u16* wfp = p.wf + ((ph == 0) ? 1 : (ph == 1) ? 2 : 3) * 16384;
        const float* rt = (ph == 0) ? p.rci : (ph == 1) ? p.rcj : p.rh;
        floatx4 ca[8] = {};
#pragma unroll
        for (int kb = 0; kb < 4; ++kb) {
            short8 a = sfrag(xt + w * TILE, 0, kb, lane);
#pragma unroll
            for (int nt = 0; nt < 8; ++nt) ca[nt] = mfma16(a, wfrag(wfp, nt, kb, lane), ca[nt]);
        }
#pragma unroll
        for (int nt = 0; nt < 8; ++nt) {
            float rc = rt[b * 128 + nt * 16 + col];
#pragma unroll
            for (int r = 0; r < 4; ++r) ca[nt][r] += rc;
        }
        if (ph == 2) {                            // t1 -> fragment-major, 8B/lane
            u64* t1f = (u64*)p.t1g;
            int tile = blk * 4 + w;               // physical tile index
#pragma unroll
            for (int nt = 0; nt < 8; ++nt) {
                u32 lo = (u32)f2bf(ca[nt][0]) | ((u32)f2bf(ca[nt][1]) << 16);
                u32 hi = (u32)f2bf(ca[nt][2]) | ((u32)f2bf(ca[nt][3]) << 16);
                t1f[(size_t)(tile * 8 + nt) * 64 + lane] = (u64)lo | ((u64)hi << 32);
            }
        } else if (ph == 0) {                     // ci1: physical rows, contiguous
            tile_store(ob + w * TILE, ca, lane);
            WVB();
            tile_flush(ob + w * TILE, p.ci1 + (size_t)rowbase * 128, lane);
            WVB();
        } else {                                  // cj1: scatter to ORIGINAL q
            tile_store(ob + w * TILE, ca, lane);
            WVB();
#pragma unroll
            for (int it = 0; it < 4; ++it) {
                int chunk = it * 64 + lane, row = chunk >> 4, c8 = chunk & 15;
                int q = qmap[w * 16 + row];
                *(uint4*)(p.cj1 + ((size_t)b * NQ_ + q) * 128 + c8 * 8) =
                    *(const uint4*)(ob + w * TILE + row * LDP + c8 * 8);
            }
            WVB();
        }
    }
}

// ---------------------------------------------------------------------------
// node1, 1024 blocks x 4 waves x 16 rows (sorted): fused round-1 gather
// (lean/tail, 8 in flight) -> x1 GEMM; t1 fragment-major; LN;
// out += mean(x1@n2_1); fin GEMV. XCD-swizzled (cj1[b] L2-resident).
// ---------------------------------------------------------------------------
__global__ __launch_bounds__(256, 4) void k_node1(P p) {
    __shared__ __align__(16) char smem[35072];
    u16* xt = (u16*)smem;
    u16* ob = (u16*)(smem + 17408);
    int* qmap = (int*)(smem + 34816);
    int tid = threadIdx.x, lane = tid & 63, w = tid >> 6;
    int col = lane & 15, qd = lane >> 4;
    int blk = blk_swz();
    int rowbase = blk * 64 + w * 16;
    int b = blk >> 4;
    load_qmap(qmap, p.perm, blk, w, lane);

    // ---- fused round-1 edge aggregation (sorted, lean/tail) ----
    {
        float2 wl2 = ((const float2*)(p.wl + 128))[lane];
        const u32* cip = (const u32*)p.ci1;
        const u32* cjp = (const u32*)p.cj1 + (size_t)b * NQ_ * 64;
        for (int g2 = 0; g2 < 2; ++g2) {
            int st[8], en[8];
            float ax[8] = {}, ay[8] = {}, cx[8], cy[8];
#pragma unroll
            for (int j = 0; j < 8; ++j) {
                int prow = rowbase + g2 * 8 + j;
                u32 cv = cip[(size_t)prow * 64 + lane];
                cx[j] = bf2f((u16)(cv & 0xffffu)); cy[j] = bf2f((u16)(cv >> 16));
                int q = qmap[w * 16 + g2 * 8 + j];
                st[j] = p.ofs[q]; en[j] = p.ofs[q + 1];
            }
            int mn = en[0] - st[0], mx = mn;
#pragma unroll
            for (int j = 1; j < 8; ++j) {
                mn = imin2(mn, en[j] - st[j]); mx = imax2(mx, en[j] - st[j]);
            }
            int tc[8]; float ac[8];
#pragma unroll
            for (int j = 0; j < 8; ++j) {         // clamped init prefetch
                int last = en[j] - 1;
                int safe = st[j] < en[j] ? st[j] : (last >= 0 ? last : 0);
                int2 tv = p.ta[safe];
                tc[j] = tv.x; ac[j] = __int_as_float(tv.y);
            }
            for (int k2 = 0; k2 < mn; ++k2) {     // lean path
                u32 jv[8];
#pragma unroll
                for (int j = 0; j < 8; ++j) jv[j] = cjp[(u32)(tc[j] + lane)];
                int2 tv[8];
#pragma unroll
                for (int j = 0; j < 8; ++j) tv[j] = p.ta[st[j] + k2 + 1];
#pragma unroll
                for (int j = 0; j < 8; ++j) {
                    ax[j] += fmaxf(cx[j] + bf2f_lo(jv[j]) + ac[j] * wl2.x, 0.f);
                    ay[j] += fmaxf(cy[j] + bf2f_hi(jv[j]) + ac[j] * wl2.y, 0.f);
                    tc[j] = tv[j].x; ac[j] = __int_as_float(tv[j].y);
                }
            }
            for (int k2 = mn; k2 < mx; ++k2) {    // masked tail
                u32 jv[8];
#pragma unroll
                for (int j = 0; j < 8; ++j) jv[j] = cjp[(u32)(tc[j] + lane)];
                int2 tv[8];
#pragma unroll
                for (int j = 0; j < 8; ++j) {
                    int idx = st[j] + k2 + 1, last = en[j] - 1;
                    int safe = idx < en[j] ? idx : (last >= 0 ? last : 0);
                    tv[j] = p.ta[safe];
                }
#pragma unroll
                for (int j = 0; j < 8; ++j) {
                    bool v = st[j] + k2 < en[j];
                    float vx = fmaxf(cx[j] + bf2f_lo(jv[j]) + ac[j] * wl2.x, 0.f);
                    float vy = fmaxf(cy[j] + bf2f_hi(jv[j]) + ac[j] * wl2.y, 0.f);
                    ax[j] += v ? vx : 0.f;
                    ay[j] += v ? vy : 0.f;
                    tc[j] = tv[j].x; ac[j] = __int_as_float(tv[j].y);
                }
            }
#pragma unroll
            for (int j = 0; j < 8; ++j) {
                int r = g2 * 8 + j;
                u32* tp = (u32*)(xt + (size_t)w * TILE + r * LDP);
                tp[lane] = (u32)f2bf(ax[j]) | ((u32)f2bf(ay[j]) << 16);
            }
        }
    }
    WVB();

    const u16* wc1 = p.wf + 4 * 16384;
    floatx4 xa[8] = {};
#pragma unroll
    for (int kb = 0; kb < 4; ++kb) {
        short8 a = sfrag(xt + w * TILE, 0, kb, lane);
#pragma unroll
        for (int nt = 0; nt < 8; ++nt) xa[nt] = mfma16(a, wfrag(wc1, nt, kb, lane), xa[nt]);
    }
    const float* vb21 = p.vb2 + 128;
    const u64* t1f = (const u64*)p.t1g;
    int tile = blk * 4 + w;                       // physical tile index
#pragma unroll
    for (int nt = 0; nt < 8; ++nt) {
        int cg = nt * 16 + col;
        float vb = vb21[cg];
        u64 tv = t1f[(size_t)(tile * 8 + nt) * 64 + lane];   // coalesced 8B/lane
        float tvf[4] = { bf2f((u16)tv),         bf2f((u16)(tv >> 16)),
                         bf2f((u16)(tv >> 32)), bf2f((u16)(tv >> 48)) };
#pragma unroll
        for (int r = 0; r < 4; ++r) {
            int q = qmap[w * 16 + qd * 4 + r];
            xa[nt][r] = fmaxf(xa[nt][r] + tvf[r] + p.degf[q] * vb, 0.f);
        }
    }
#pragma unroll
    for (int r = 0; r < 4; ++r) {
        float s = 0.f, s2 = 0.f;
#pragma unroll
        for (int nt = 0; nt < 8; ++nt) { float v = xa[nt][r]; s += v; s2 += v * v; }
#pragma unroll
        for (int o = 1; o < 16; o <<= 1) { s += __shfl_xor(s, o, 64); s2 += __shfl_xor(s2, o, 64); }
        float mu = s * (1.f / 128.f), var = s2 * (1.f / 128.f) - mu * mu;
        float rs = rsqrtf(var + 1e-5f);
#pragma unroll
        for (int nt = 0; nt < 8; ++nt) {
            int cg = nt * 16 + col;
            xa[nt][r] = (xa[nt][r] - mu) * rs * p.ln_g[128 + cg] + p.ln_b[128 + cg];
        }
    }
    // mean(x1@n2_1): per-wave staging through ob slot
    const u16* n21 = p.wf + 5 * 16384;
    float s8[8] = {};
    tile_store(ob + w * TILE, xa, lane);
    WVB();
    {
        floatx4 ma[8] = {};
#pragma unroll
        for (int kb = 0; kb < 4; ++kb) {
            short8 a = sfrag(ob + w * TILE, 0, kb, lane);
#pragma unroll
            for (int nt = 0; nt < 8; ++nt) ma[nt] = mfma16(a, wfrag(n21, nt, kb, lane), ma[nt]);
        }
#pragma unroll
        for (int nt = 0; nt < 8; ++nt)
#pragma unroll
            for (int r = 0; r < 4; ++r) s8[nt] += ma[nt][r];
    }
#pragma unroll
    for (int nt = 0; nt < 8; ++nt) {
        s8[nt] += __shfl_xor(s8[nt], 16, 64);
        s8[nt] += __shfl_xor(s8[nt], 32, 64);
    }
    if (lane < 16) {
#pragma unroll
        for (int nt = 0; nt < 8; ++nt)
            atomicAdd(p.out + b * 128 + nt * 16 + lane, s8[nt] * (1.f / 1024.f));
    }
    // fin: out[b] += z0[b] + n_b2_0 + n_b2_1 + mx0[b]@n2_0^T / 1024  (vectorized)
    if ((blk & 15) == 0 && tid < 128) {
        int c = tid;
        const float* mx = p.mx0 + b * 128;
        float s = 0.f;
#pragma unroll
        for (int k8 = 0; k8 < 16; ++k8) {
            short8 wv = *(const short8*)(p.w_n20 + c * 128 + k8 * 8);
            const float* mxp = mx + k8 * 8;
#pragma unroll
            for (int j = 0; j < 8; ++j) s += mxp[j] * bf2f((u16)wv[j]);
        }
        float acc = p.z0[b * 128 + c] + p.n_b2[c] + p.n_b2[128 + c] + s * (1.f / 1024.f);
        atomicAdd(p.out + b * 128 + c, acc);
    }
}

// ---------------------------------------------------------------------------
extern "C" void kernel_launch(void* const* d_in, const int* in_sizes, int n_in,
                              void* d_out, int out_size, void* d_ws, size_t ws_size,
                              hipStream_t stream) {
    P p;
    p.z0   = (const float*)d_in[0];
    p.ei   = (const int*)d_in[1];
    p.attr = (const float*)d_in[2];
    p.e_w1 = (const float*)d_in[4];
    p.e_b1 = (const float*)d_in[5];
    p.e_w2 = (const float*)d_in[6];
    p.e_b2 = (const float*)d_in[7];
    p.n_w1 = (const float*)d_in[8];
    p.n_b1 = (const float*)d_in[9];
    p.ln_g = (const float*)d_in[10];
    p.ln_b = (const float*)d_in[11];
    p.n_w2 = (const float*)d_in[12];
    p.n_b2 = (const float*)d_in[13];
    p.out  = (float*)d_out;

    const size_t H = (size_t)M_ * L_;
    float* f  = (float*)d_ws;
    p.degf = f;                           // 1024
    p.wl   = f + 1024;                    // 256
    p.vb2  = p.wl + 256;                  // 256
    p.rx   = p.vb2 + 256;                 // 8192
    p.rci  = p.rx + 8192;                 // 8192
    p.rcj  = p.rci + 8192;                // 8192
    p.rh   = p.rcj + 8192;                // 8192
    p.mx0  = p.rh + 8192;                 // 8192
    p.ofs  = (int*)(p.mx0 + 8192);        // 1056
    p.perm = p.ofs + 1056;                // 1024
    p.ta   = (int2*)(p.perm + 1024);      // E_+8 int2 (8B-aligned)
    p.wf    = (u16*)(p.ta + E_ + 8);      // 6*16384
    p.w_n20 = p.wf + 6 * 16384;           // 16384
    p.c0t   = p.w_n20 + 16384;            // 8192
    p.t1g   = p.c0t + 8192;               // H (fragment-major)
    p.ci1   = p.t1g + H;                  // H
    p.cj1   = p.ci1 + H;                  // H

    hipMemsetAsync(p.out, 0, 8192 * sizeof(float), stream);

    k_setup<<<20, 256, 0, stream>>>(p);
    k_node0<<<1024, 256, 0, stream>>>(p);
    k_node1<<<1024, 256, 0, stream>>>(p);
}